// Round 1
// baseline (284.596 us; speedup 1.0000x reference)
//
#include <hip/hip_runtime.h>
#include <math.h>

#define CH    64
#define WW    192
#define HH    192
#define HWSZ  (192*192)
#define KK    49
#define ROWP  68   // padded fp32 LDS row (dwords)
#define SROW  72   // bf16 row stride in shorts (144B)
#define C3ROW 72   // conv3 staged px stride (shorts)
#define OROW  136  // k_out staged px stride (shorts, 128ch + 8 pad)

typedef __attribute__((ext_vector_type(8))) short s16x8;   // 8 bf16 = 4 VGPR
typedef __attribute__((ext_vector_type(4))) float f32x4;

__device__ __forceinline__ unsigned short f2bf(float f) {
    union { float f; unsigned u; } v; v.f = f;
    unsigned u = v.u + 0x7FFFu + ((v.u >> 16) & 1u);   // RNE
    return (unsigned short)(u >> 16);
}

// pack two floats to bf16x2 (round-half-up): 2 adds + 1 v_perm
__device__ __forceinline__ unsigned pkbf(float lo, float hi) {
    return __builtin_amdgcn_perm(__float_as_uint(hi) + 0x8000u,
                                 __float_as_uint(lo) + 0x8000u, 0x07060302u);
}

// ---------------------------------------------------------------------------
// k_prep (grid 49 x 256): krT + A-fragment packs (wA, w2A, wpoA, wpiA)
// ---------------------------------------------------------------------------
__device__ const float c_cos8[8] = {
    1.f, 0.70710678118654752f, 0.f, -0.70710678118654752f,
   -1.f, -0.70710678118654752f, 0.f, 0.70710678118654752f };

__global__ __launch_bounds__(256) void k_prep(
    const float* __restrict__ fw,   // [64,1,1,8,5]
    const float* __restrict__ wd,   // [64,64,7,7]
    const float* __restrict__ w2,   // [64,64,3,3]
    const float* __restrict__ wc1,  // [64,64,1,1]
    const float* __restrict__ wpo,  // [128,128]
    const float* __restrict__ wpi,  // [64,64]
    float* __restrict__ krT,        // [64 uv][64 c]
    short* __restrict__ wA,         // [49*8*512]
    short* __restrict__ w2A,        // [9*8*512]
    short* __restrict__ wpoA,       // [32*512]
    short* __restrict__ wpiA)       // [8*512]
{
    int tid = blockIdx.x * blockDim.x + threadIdx.x;
    int nt  = gridDim.x * blockDim.x;
    for (int t = tid; t < 64 * 64; t += nt) {
        int uv = t >> 6, c = t & 63;
        int u = uv >> 3, v = uv & 7;
        float acc = 0.f;
        for (int ky = 0; ky < 8; ky++)
            for (int kx = 0; kx < 8; kx++) {
                float wv = (kx <= 4) ? fw[c * 40 + ky * 5 + kx]
                                     : fw[c * 40 + ((8 - ky) & 7) * 5 + (8 - kx)];
                acc += wv * c_cos8[(ky * u + kx * v) & 7];
            }
        krT[uv * 64 + c] = acc * (1.f / 64.f);
    }
    for (int t = tid; t < 9 * 4096; t += nt) {
        int tap = t / 4096, rem = t & 4095;
        int o = rem >> 6, c = rem & 63;
        float v = w2[(o * 64 + c) * 9 + tap];
        int fi = tap * 8 + (o >> 4) * 2 + (c >> 5);
        int ln = ((c >> 3) & 3) * 16 + (o & 15);
        w2A[fi * 512 + ln * 8 + (c & 7)] = (short)f2bf(v);
    }
    for (int t = tid; t < 128 * 128; t += nt) {
        int o = t >> 7, c = t & 127;
        int fi = (o >> 4) * 4 + (c >> 5);
        int ln = ((c >> 3) & 3) * 16 + (o & 15);
        wpoA[fi * 512 + ln * 8 + (c & 7)] = (short)f2bf(wpo[t]);
    }
    for (int t = tid; t < 64 * 64; t += nt) {
        int o = t >> 6, c = t & 63;
        int fi = (o >> 4) * 2 + (c >> 5);
        int ln = ((c >> 3) & 3) * 16 + (o & 15);
        wpiA[fi * 512 + ln * 8 + (c & 7)] = (short)f2bf(wpi[t]);
    }

    // ---- fold wc1 @ wd + pack: one block per tap k ----
    __shared__ float wdk [64 * ROWP];
    __shared__ float wc1s[64 * ROWP];
    int k = blockIdx.x;
    int t = threadIdx.x;
#pragma unroll
    for (int r = 0; r < 16; r++) {
        int idx = t + r * 256;
        int o = idx >> 6, c = idx & 63;
        wdk [o * ROWP + c] = wd[(o * 64 + c) * KK + k];
        wc1s[o * ROWP + c] = wc1[o * 64 + c];
    }
    __syncthreads();

    int ot = (t >> 4) * 4, cb = (t & 15) * 4;
    float a[4][4];
#pragma unroll
    for (int i = 0; i < 4; i++)
#pragma unroll
        for (int j = 0; j < 4; j++) a[i][j] = 0.f;
    for (int o = 0; o < 64; o++) {
        float wv_[4], sv_[4];
#pragma unroll
        for (int i = 0; i < 4; i++) wv_[i] = wc1s[(ot + i) * ROWP + o];
#pragma unroll
        for (int j = 0; j < 4; j++) sv_[j] = wdk[o * ROWP + cb + j];
#pragma unroll
        for (int i = 0; i < 4; i++)
#pragma unroll
            for (int j = 0; j < 4; j++) a[i][j] += wv_[i] * sv_[j];
    }
#pragma unroll
    for (int i = 0; i < 4; i++)
#pragma unroll
        for (int j = 0; j < 4; j++) {
            int o2 = ot + i, c = cb + j;
            int tt = o2 >> 4, m = o2 & 15;
            int kt = c >> 5, q = (c >> 3) & 3, jj = c & 7;
            int ln = q * 16 + m;
            wA[(k * 8 + tt * 2 + kt) * 512 + ln * 8 + jj] = (short)f2bf(a[i][j]);
        }
}

// ---------------------------------------------------------------------------
// k_trans: enc [c][p] (fp32) -> encH [p][c] (bf16) -- halves gather bytes
// ---------------------------------------------------------------------------
__global__ __launch_bounds__(256) void k_trans(
    const float* __restrict__ enc, unsigned short* __restrict__ encH)
{
    __shared__ float s[64 * 65];
    int t = threadIdx.x;
    int base = blockIdx.x * 64;
#pragma unroll
    for (int r = 0; r < 16; r++) {
        int idx = t + r * 256;
        int p = idx & 63, c = idx >> 6;
        s[p * 65 + c] = enc[c * HWSZ + base + p];
    }
    __syncthreads();
#pragma unroll
    for (int r = 0; r < 8; r++) {
        int idx = t + r * 256;             // 2048 pair-units
        int pr = idx & 31, p = idx >> 5;   // pair 0..31, px 0..63
        ((unsigned*)encH)[(base + p) * 32 + pr] =
            pkbf(s[p * 65 + 2 * pr], s[p * 65 + 2 * pr + 1]);
    }
}

// ---------------------------------------------------------------------------
// k_deform: MFMA deformable conv, R9 structure: gather raw bf16 corners
// DIRECTLY in B-fragment layout (lane = q*16+n loads encH[corner(n)*64+q*8]),
// run 4 corner-MFMAs per output tile (zero C hoisted), blend partial outputs
// with per-pixel bilinear weights (lane-uniform in C-layout -> 16 scalar*v4
// FMAs/tap). Deletes unpack/repack/LDS-bounce from the VALU-bound hot loop;
// moves the blend reduction onto the 93%-idle MFMA pipe.
// ---------------------------------------------------------------------------
#define REDW 20   // reduction row stride (floats): 80B, 16B-aligned

__global__ __launch_bounds__(256) void k_deform(
    const unsigned short* __restrict__ encH, const float* __restrict__ off,
    const float* __restrict__ msk, const short* __restrict__ wA,
    float* __restrict__ rev)
{
    __shared__ __align__(16) float red[2 * 64 * REDW]; // 10240 B reduction

    int t = threadIdx.x;
    int lane = t & 63, w = t >> 6;
    int b = blockIdx.x;
    int xcd = b & 7, blk = b >> 3;          // 288 strips per xcd band
    int gy  = xcd * 24 + blk / 12;
    int gx0 = (blk % 12) * 16;

    int n = lane & 15, q = lane >> 4;       // B-frag / C-frag lane mapping
    int sgx  = gx0 + n;
    int gp_s = gy * WW + sgx;

    f32x4 acc[4];
#pragma unroll
    for (int ot = 0; ot < 4; ot++) acc[ot] = (f32x4){0.f, 0.f, 0.f, 0.f};
    const f32x4 zf = (f32x4){0.f, 0.f, 0.f, 0.f};   // hoisted zero C operand

    int kstart = (w == 0) ? 0 : 13 + (w - 1) * 12;
    int kend   = (w == 0) ? 13 : kstart + 12;

    float dy = off[(2 * kstart) * HWSZ + gp_s];
    float dx = off[(2 * kstart + 1) * HWSZ + gp_s];
    float mm = msk[kstart * HWSZ + gp_s];

    int ky = kstart / 7, kx = kstart % 7;

#pragma unroll 1
    for (int k = kstart; k < kend; k++) {
        float y = (float)(gy  - 3 + ky) + dy;
        float x = (float)(sgx - 3 + kx) + dx;
        float y0f = floorf(y), x0f = floorf(x);
        float wy = y - y0f, wx = x - x0f;
        int iy0 = (int)y0f, ix0 = (int)x0f;
        int iy1 = iy0 + 1, ix1 = ix0 + 1;
        bool vy0 = (iy0 >= 0) & (iy0 < HH);
        bool vy1 = (iy1 >= 0) & (iy1 < HH);
        bool vx0 = (ix0 >= 0) & (ix0 < WW);
        bool vx1 = (ix1 >= 0) & (ix1 < WW);
        int iy0c = min(max(iy0, 0), HH - 1), iy1c = min(max(iy1, 0), HH - 1);
        int ix0c = min(max(ix0, 0), WW - 1), ix1c = min(max(ix1, 0), WW - 1);
        float a00 = (vy0 & vx0) ? (1.f - wy) * (1.f - wx) * mm : 0.f;
        float a01 = (vy0 & vx1) ? (1.f - wy) * wx * mm : 0.f;
        float a10 = (vy1 & vx0) ? wy * (1.f - wx) * mm : 0.f;
        float a11 = (vy1 & vx1) ? wy * wx * mm : 0.f;

        // raw bf16 corners, directly in B-frag layout: 2x16B per corner
        int r0 = iy0c * WW, r1 = iy1c * WW;
        const unsigned short* p00 = encH + ((r0 + ix0c) << 6) + (q << 3);
        const unsigned short* p01 = encH + ((r0 + ix1c) << 6) + (q << 3);
        const unsigned short* p10 = encH + ((r1 + ix0c) << 6) + (q << 3);
        const unsigned short* p11 = encH + ((r1 + ix1c) << 6) + (q << 3);
        s16x8 b00a = *(const s16x8*)p00, b00b = *(const s16x8*)(p00 + 32);
        s16x8 b01a = *(const s16x8*)p01, b01b = *(const s16x8*)(p01 + 32);
        s16x8 b10a = *(const s16x8*)p10, b10b = *(const s16x8*)(p10 + 32);
        s16x8 b11a = *(const s16x8*)p11, b11b = *(const s16x8*)(p11 + 32);

        // prefetch next-tap offsets
        float dyn = 0.f, dxn = 0.f, mmn = 0.f;
        if (k + 1 < kend) {
            dyn = off[(2 * k + 2) * HWSZ + gp_s];
            dxn = off[(2 * k + 3) * HWSZ + gp_s];
            mmn = msk[(k + 1) * HWSZ + gp_s];
        }

        // per corner: raw-data MFMA (zero C-in); blend partial outputs with
        // lane-uniform bilinear weights in f32
#pragma unroll
        for (int ot = 0; ot < 4; ot++) {
            s16x8 af0 = *(const s16x8*)&wA[(k * 8 + ot * 2 + 0) * 512 + lane * 8];
            s16x8 af1 = *(const s16x8*)&wA[(k * 8 + ot * 2 + 1) * 512 + lane * 8];
            f32x4 t00 = __builtin_amdgcn_mfma_f32_16x16x32_bf16(af0, b00a, zf, 0, 0, 0);
            t00       = __builtin_amdgcn_mfma_f32_16x16x32_bf16(af1, b00b, t00, 0, 0, 0);
            f32x4 t01 = __builtin_amdgcn_mfma_f32_16x16x32_bf16(af0, b01a, zf, 0, 0, 0);
            t01       = __builtin_amdgcn_mfma_f32_16x16x32_bf16(af1, b01b, t01, 0, 0, 0);
            f32x4 t10 = __builtin_amdgcn_mfma_f32_16x16x32_bf16(af0, b10a, zf, 0, 0, 0);
            t10       = __builtin_amdgcn_mfma_f32_16x16x32_bf16(af1, b10b, t10, 0, 0, 0);
            f32x4 t11 = __builtin_amdgcn_mfma_f32_16x16x32_bf16(af0, b11a, zf, 0, 0, 0);
            t11       = __builtin_amdgcn_mfma_f32_16x16x32_bf16(af1, b11b, t11, 0, 0, 0);
#pragma unroll
            for (int r = 0; r < 4; r++)
                acc[ot][r] += a00 * t00[r] + a01 * t01[r]
                            + a10 * t10[r] + a11 * t11[r];
        }

        dy = dyn; dx = dxn; mm = mmn;
        kx++; if (kx == 7) { kx = 0; ky++; }
    }

    // two-phase tree reduction (2-slot buffer)
    if (w >= 2) {
        float* rp = &red[((w - 2) * 64 + lane) * REDW];
#pragma unroll
        for (int ot = 0; ot < 4; ot++)
            *(float4*)&rp[ot * 4] = make_float4(acc[ot][0], acc[ot][1], acc[ot][2], acc[ot][3]);
    }
    __syncthreads();
    if (w < 2) {
        const float* rp = &red[(w * 64 + lane) * REDW];
#pragma unroll
        for (int ot = 0; ot < 4; ot++) {
            float4 v = *(const float4*)&rp[ot * 4];
            acc[ot][0] += v.x; acc[ot][1] += v.y;
            acc[ot][2] += v.z; acc[ot][3] += v.w;
        }
    }
    __syncthreads();
    if (w == 1) {
        float* rp = &red[lane * REDW];
#pragma unroll
        for (int ot = 0; ot < 4; ot++)
            *(float4*)&rp[ot * 4] = make_float4(acc[ot][0], acc[ot][1], acc[ot][2], acc[ot][3]);
    }
    __syncthreads();
    if (w == 0) {
        const float* rp = &red[lane * REDW];
#pragma unroll
        for (int ot = 0; ot < 4; ot++) {
            float4 v = *(const float4*)&rp[ot * 4];
            acc[ot][0] += v.x; acc[ot][1] += v.y;
            acc[ot][2] += v.z; acc[ot][3] += v.w;
        }
        int gp_m = gy * WW + gx0 + n;
#pragma unroll
        for (int ot = 0; ot < 4; ot++) {
            float4 rv = make_float4(acc[ot][0], acc[ot][1], acc[ot][2], acc[ot][3]);
            *(float4*)&rev[gp_m * 64 + ot * 16 + q * 4] = rv;
        }
    }
}

// ---------------------------------------------------------------------------
// k_fft: per 8x8 patch: proj_in via MFMA bf16, then circular conv (fp32).
// Stages straight from bf16 encH (plain 16B copies, no packing).
// ---------------------------------------------------------------------------
__global__ __launch_bounds__(256) void k_fft(
    const unsigned short* __restrict__ encH, const short* __restrict__ wpiA,
    const float* __restrict__ krT, float* __restrict__ e1)
{
    __shared__ __align__(16) short sbf[64 * SROW];   // bf16 enc [px][c]
    __shared__ __align__(16) float e0[64 * ROWP];    // fp32 [px][o]
    int t = threadIdx.x;
    int pbx = blockIdx.x % 24, pby = blockIdx.x / 24;
    int gx0 = pbx * 8, gy0 = pby * 8;

#pragma unroll
    for (int r = 0; r < 2; r++) {
        int idx = t + r * 256;             // 512 x 8-ch units
        int px = idx >> 3, g8 = idx & 7;
        int gy = gy0 + (px >> 3), gx = gx0 + (px & 7);
        *(uint4*)&sbf[px * SROW + g8 * 8] =
            *(const uint4*)&encH[(gy * WW + gx) * 64 + g8 * 8];
    }
    __syncthreads();

    int lane = t & 63, w = t >> 6;
    int n = lane & 15, q = lane >> 4;
    s16x8 a0 = *(const s16x8*)&wpiA[(w * 2 + 0) * 512 + lane * 8];
    s16x8 a1 = *(const s16x8*)&wpiA[(w * 2 + 1) * 512 + lane * 8];
#pragma unroll
    for (int j = 0; j < 4; j++) {
        s16x8 b0 = *(const s16x8*)&sbf[(j * 16 + n) * SROW +  0 + q * 8];
        s16x8 b1 = *(const s16x8*)&sbf[(j * 16 + n) * SROW + 32 + q * 8];
        f32x4 acc = {0.f, 0.f, 0.f, 0.f};
        acc = __builtin_amdgcn_mfma_f32_16x16x32_bf16(a0, b0, acc, 0, 0, 0);
        acc = __builtin_amdgcn_mfma_f32_16x16x32_bf16(a1, b1, acc, 0, 0, 0);
#pragma unroll
        for (int r = 0; r < 4; r++)
            e0[(j * 16 + n) * ROWP + w * 16 + q * 4 + r] = acc[r];
    }
    __syncthreads();

    int o = t & 63;
    int yb = t >> 6;
#pragma unroll
    for (int yy = 0; yy < 2; yy++) {
        int y = yb + yy * 4;
        float outr[8];
#pragma unroll
        for (int x = 0; x < 8; x++) outr[x] = 0.f;
#pragma unroll
        for (int u = 0; u < 8; u++) {
            int ry = (y - u + 8) & 7;
            float row[8];
#pragma unroll
            for (int rx = 0; rx < 8; rx++)
                row[rx] = e0[(ry * 8 + rx) * ROWP + o];
#pragma unroll
            for (int v = 0; v < 8; v++) {
                float kv = krT[(u * 8 + v) * 64 + o];
#pragma unroll
                for (int x = 0; x < 8; x++)
                    outr[x] += kv * row[(x - v + 8) & 7];
            }
        }
        int gy = gy0 + y;
#pragma unroll
        for (int x = 0; x < 8; x++)
            e1[(gy * WW + gx0 + x) * 64 + o] = outr[x];
    }
}

// ---------------------------------------------------------------------------
// k_c3out: fused conv3x3(e1+rev) -> [.,dec] -> proj_out -> SimpleGate.
// ---------------------------------------------------------------------------
__global__ __launch_bounds__(256) void k_c3out(
    const float* __restrict__ e1, const float* __restrict__ rev,
    const short* __restrict__ w2A, const float* __restrict__ dec,
    const short* __restrict__ wpoA, float* __restrict__ out)
{
    __shared__ __align__(16) short sm[4][54 * C3ROW];  // per-wave: 3 rows x 18 px
    int t = threadIdx.x;
    int lane = t & 63, w = t >> 6;
    int b = blockIdx.x;
    int xcd = b & 7, blk = b >> 3;
    int gy  = xcd * 24 + blk / 3;
    int gx0 = (blk % 3) * 64 + w * 16;
    short* smw = &sm[w][0];
    int n = lane & 15, q = lane >> 4;

    for (int r = 0; r < 14; r++) {
        int u = lane + r * 64;
        if (u < 864) {
            int rp = u >> 4, g = u & 15;
            int row = rp / 18, pxl = rp - row * 18;
            int gyy = gy + row - 1, gxx = gx0 + pxl - 1;
            float4 v = make_float4(0.f, 0.f, 0.f, 0.f);
            if (gyy >= 0 && gyy < HH && gxx >= 0 && gxx < WW) {
                int gp = (gyy * WW + gxx) * 64 + g * 4;
                float4 va = *(const float4*)&e1[gp];
                float4 vb = *(const float4*)&rev[gp];
                v.x = va.x + vb.x; v.y = va.y + vb.y;
                v.z = va.z + vb.z; v.w = va.w + vb.w;
            }
            *(uint2*)&smw[rp * C3ROW + g * 4] = make_uint2(pkbf(v.x, v.y), pkbf(v.z, v.w));
        }
    }

    f32x4 acc[4];
#pragma unroll
    for (int ot = 0; ot < 4; ot++) acc[ot] = (f32x4){0.f, 0.f, 0.f, 0.f};

#pragma unroll 1
    for (int tap = 0; tap < 9; tap++) {
        int dy = tap / 3, dx = tap - dy * 3;
        int rp = dy * 18 + n + dx;
        s16x8 b0 = *(const s16x8*)&smw[rp * C3ROW +  0 + q * 8];
        s16x8 b1 = *(const s16x8*)&smw[rp * C3ROW + 32 + q * 8];
#pragma unroll
        for (int ot = 0; ot < 4; ot++) {
            s16x8 a0 = *(const s16x8*)&w2A[(tap * 8 + ot * 2 + 0) * 512 + lane * 8];
            s16x8 a1 = *(const s16x8*)&w2A[(tap * 8 + ot * 2 + 1) * 512 + lane * 8];
            acc[ot] = __builtin_amdgcn_mfma_f32_16x16x32_bf16(a0, b0, acc[ot], 0, 0, 0);
            acc[ot] = __builtin_amdgcn_mfma_f32_16x16x32_bf16(a1, b1, acc[ot], 0, 0, 0);
        }
    }

    // fused proj_out: stage e3 (C-layout regs) + dec into B-frag rows
#pragma unroll
    for (int ot = 0; ot < 4; ot++) {
        unsigned lo = pkbf(acc[ot][0], acc[ot][1]);
        unsigned hi = pkbf(acc[ot][2], acc[ot][3]);
        *(uint2*)&smw[n * OROW + ot * 16 + q * 4] = make_uint2(lo, hi);
    }
    {
        int gp = gy * WW + gx0 + n;
        unsigned pk[8];
#pragma unroll
        for (int i = 0; i < 8; i++) {
            float va = dec[(q * 16 + 2 * i)     * HWSZ + gp];
            float vb = dec[(q * 16 + 2 * i + 1) * HWSZ + gp];
            pk[i] = pkbf(va, vb);
        }
        *(uint4*)&smw[n * OROW + 64 + q * 16]     = make_uint4(pk[0], pk[1], pk[2], pk[3]);
        *(uint4*)&smw[n * OROW + 64 + q * 16 + 8] = make_uint4(pk[4], pk[5], pk[6], pk[7]);
    }

    f32x4 go[8];
#pragma unroll
    for (int ot = 0; ot < 8; ot++) go[ot] = (f32x4){0.f, 0.f, 0.f, 0.f};

#pragma unroll 1
    for (int kt = 0; kt < 4; kt++) {
        s16x8 bb = *(const s16x8*)&smw[n * OROW + kt * 32 + q * 8];
#pragma unroll
        for (int ot = 0; ot < 8; ot++) {
            s16x8 aa = *(const s16x8*)&wpoA[(ot * 4 + kt) * 512 + lane * 8];
            go[ot] = __builtin_amdgcn_mfma_f32_16x16x32_bf16(aa, bb, go[ot], 0, 0, 0);
        }
    }

    int gp = gy * WW + gx0 + n;
#pragma unroll
    for (int ot = 0; ot < 4; ot++)
#pragma unroll
        for (int r = 0; r < 4; r++)
            out[(ot * 16 + q * 4 + r) * HWSZ + gp] = go[ot][r] * go[ot + 4][r];
}

// ---------------------------------------------------------------------------
extern "C" void kernel_launch(void* const* d_in, const int* in_sizes, int n_in,
                              void* d_out, int out_size, void* d_ws, size_t ws_size,
                              hipStream_t stream)
{
    const float* enc  = (const float*)d_in[0];
    const float* dec  = (const float*)d_in[1];
    const float* ioff = (const float*)d_in[2];
    const float* iwt  = (const float*)d_in[3];
    const float* wpi  = (const float*)d_in[4];
    const float* fw   = (const float*)d_in[5];
    const float* wpo  = (const float*)d_in[6];
    const float* wd   = (const float*)d_in[7];
    const float* wc1  = (const float*)d_in[8];
    const float* wc2  = (const float*)d_in[9];
    float* out = (float*)d_out;
    float* ws  = (float*)d_ws;

    float*          krT  = ws;                           //    4096
    float*          rev  = ws + 4096;                    // 2359296  [px][64]
    float*          e1   = ws + 2363392;                 // 2359296  [px][64]
    unsigned short* encH = (unsigned short*)(ws + 4722688); // 2359296 bf16 (1179648 fl)
    short*          wA   = (short*)(ws + 5902336);       // 200704 bf16
    short*          w2A  = (short*)(ws + 6002688);       //  36864 bf16
    short*          wpoA = (short*)(ws + 6021120);       //  16384 bf16
    short*          wpiA = (short*)(ws + 6029312);       //   4096 bf16

    hipLaunchKernelGGL(k_prep,   dim3(49),   dim3(256), 0, stream,
                       fw, wd, wc2, wc1, wpo, wpi, krT, wA, w2A, wpoA, wpiA);
    hipLaunchKernelGGL(k_trans,  dim3(576),  dim3(256), 0, stream, enc, encH);
    hipLaunchKernelGGL(k_deform, dim3(2304), dim3(256), 0, stream, encH, ioff, iwt, wA, rev);
    hipLaunchKernelGGL(k_fft,    dim3(576),  dim3(256), 0, stream, encH, wpiA, krT, e1);
    hipLaunchKernelGGL(k_c3out,  dim3(576),  dim3(256), 0, stream, e1, rev, w2A, dec, wpoA, out);
}

// Round 3
// 274.571 us; speedup vs baseline: 1.0365x; 1.0365x over previous
//
#include <hip/hip_runtime.h>
#include <math.h>

#define CH    64
#define WW    192
#define HH    192
#define HWSZ  (192*192)
#define KK    49
#define ROWP  68   // padded fp32 LDS row (dwords)
#define SROW  72   // f16 row stride in shorts (144B)
#define C3ROW 72   // conv3 staged px stride (shorts)
#define OROW  136  // k_out staged px stride (shorts, 128ch + 8 pad)

typedef __attribute__((ext_vector_type(8))) short     s16x8;
typedef __attribute__((ext_vector_type(8))) _Float16  h16x8;  // 8 f16 = 4 VGPR
typedef __attribute__((ext_vector_type(2))) _Float16  h16x2;
typedef __attribute__((ext_vector_type(2))) __fp16    fp16x2; // cvt_pkrtz result type
typedef __attribute__((ext_vector_type(4))) float     f32x4;

__device__ __forceinline__ unsigned short f2h(float f) {
    union { _Float16 h; unsigned short s; } u; u.h = (_Float16)f;  // RNE
    return u.s;
}

// pack two floats to f16x2 (RTZ, single v_cvt_pkrtz_f16_f32)
__device__ __forceinline__ unsigned pkh(float lo, float hi) {
    union { fp16x2 h; unsigned u; } v;
    v.h = __builtin_amdgcn_cvt_pkrtz(lo, hi);
    return v.u;
}

// broadcast one float into packed f16x2 (for pk_fma weights)
__device__ __forceinline__ h16x2 cvt2h(float a) {
    union { fp16x2 h; h16x2 o; } v;
    v.h = __builtin_amdgcn_cvt_pkrtz(a, a);
    return v.o;
}

__device__ __forceinline__ h16x2 as_h2(unsigned u) {
    union { unsigned u; h16x2 h; } v; v.u = u; return v.h;
}

// ---------------------------------------------------------------------------
// k_prep (grid 49 x 256): krT + A-fragment packs (wA, w2A, wpoA, wpiA), f16
// ---------------------------------------------------------------------------
__device__ const float c_cos8[8] = {
    1.f, 0.70710678118654752f, 0.f, -0.70710678118654752f,
   -1.f, -0.70710678118654752f, 0.f, 0.70710678118654752f };

__global__ __launch_bounds__(256) void k_prep(
    const float* __restrict__ fw,   // [64,1,1,8,5]
    const float* __restrict__ wd,   // [64,64,7,7]
    const float* __restrict__ w2,   // [64,64,3,3]
    const float* __restrict__ wc1,  // [64,64,1,1]
    const float* __restrict__ wpo,  // [128,128]
    const float* __restrict__ wpi,  // [64,64]
    float* __restrict__ krT,        // [64 uv][64 c]
    short* __restrict__ wA,         // [49*8*512]
    short* __restrict__ w2A,        // [9*8*512]
    short* __restrict__ wpoA,       // [32*512]
    short* __restrict__ wpiA)       // [8*512]
{
    int tid = blockIdx.x * blockDim.x + threadIdx.x;
    int nt  = gridDim.x * blockDim.x;
    for (int t = tid; t < 64 * 64; t += nt) {
        int uv = t >> 6, c = t & 63;
        int u = uv >> 3, v = uv & 7;
        float acc = 0.f;
        for (int ky = 0; ky < 8; ky++)
            for (int kx = 0; kx < 8; kx++) {
                float wv = (kx <= 4) ? fw[c * 40 + ky * 5 + kx]
                                     : fw[c * 40 + ((8 - ky) & 7) * 5 + (8 - kx)];
                acc += wv * c_cos8[(ky * u + kx * v) & 7];
            }
        krT[uv * 64 + c] = acc * (1.f / 64.f);
    }
    for (int t = tid; t < 9 * 4096; t += nt) {
        int tap = t / 4096, rem = t & 4095;
        int o = rem >> 6, c = rem & 63;
        float v = w2[(o * 64 + c) * 9 + tap];
        int fi = tap * 8 + (o >> 4) * 2 + (c >> 5);
        int ln = ((c >> 3) & 3) * 16 + (o & 15);
        w2A[fi * 512 + ln * 8 + (c & 7)] = (short)f2h(v);
    }
    for (int t = tid; t < 128 * 128; t += nt) {
        int o = t >> 7, c = t & 127;
        int fi = (o >> 4) * 4 + (c >> 5);
        int ln = ((c >> 3) & 3) * 16 + (o & 15);
        wpoA[fi * 512 + ln * 8 + (c & 7)] = (short)f2h(wpo[t]);
    }
    for (int t = tid; t < 64 * 64; t += nt) {
        int o = t >> 6, c = t & 63;
        int fi = (o >> 4) * 2 + (c >> 5);
        int ln = ((c >> 3) & 3) * 16 + (o & 15);
        wpiA[fi * 512 + ln * 8 + (c & 7)] = (short)f2h(wpi[t]);
    }

    // ---- fold wc1 @ wd + pack: one block per tap k ----
    __shared__ float wdk [64 * ROWP];
    __shared__ float wc1s[64 * ROWP];
    int k = blockIdx.x;
    int t = threadIdx.x;
#pragma unroll
    for (int r = 0; r < 16; r++) {
        int idx = t + r * 256;
        int o = idx >> 6, c = idx & 63;
        wdk [o * ROWP + c] = wd[(o * 64 + c) * KK + k];
        wc1s[o * ROWP + c] = wc1[o * 64 + c];
    }
    __syncthreads();

    int ot = (t >> 4) * 4, cb = (t & 15) * 4;
    float a[4][4];
#pragma unroll
    for (int i = 0; i < 4; i++)
#pragma unroll
        for (int j = 0; j < 4; j++) a[i][j] = 0.f;
    for (int o = 0; o < 64; o++) {
        float wv_[4], sv_[4];
#pragma unroll
        for (int i = 0; i < 4; i++) wv_[i] = wc1s[(ot + i) * ROWP + o];
#pragma unroll
        for (int j = 0; j < 4; j++) sv_[j] = wdk[o * ROWP + cb + j];
#pragma unroll
        for (int i = 0; i < 4; i++)
#pragma unroll
            for (int j = 0; j < 4; j++) a[i][j] += wv_[i] * sv_[j];
    }
#pragma unroll
    for (int i = 0; i < 4; i++)
#pragma unroll
        for (int j = 0; j < 4; j++) {
            int o2 = ot + i, c = cb + j;
            int tt = o2 >> 4, m = o2 & 15;
            int kt = c >> 5, q = (c >> 3) & 3, jj = c & 7;
            int ln = q * 16 + m;
            wA[(k * 8 + tt * 2 + kt) * 512 + ln * 8 + jj] = (short)f2h(a[i][j]);
        }
}

// ---------------------------------------------------------------------------
// k_trans: enc [c][p] (fp32) -> encH [p][c] (f16) -- halves gather bytes
// ---------------------------------------------------------------------------
__global__ __launch_bounds__(256) void k_trans(
    const float* __restrict__ enc, unsigned short* __restrict__ encH)
{
    __shared__ float s[64 * 65];
    int t = threadIdx.x;
    int base = blockIdx.x * 64;
#pragma unroll
    for (int r = 0; r < 16; r++) {
        int idx = t + r * 256;
        int p = idx & 63, c = idx >> 6;
        s[p * 65 + c] = enc[c * HWSZ + base + p];
    }
    __syncthreads();
#pragma unroll
    for (int r = 0; r < 8; r++) {
        int idx = t + r * 256;             // 2048 pair-units
        int pr = idx & 31, p = idx >> 5;   // pair 0..31, px 0..63
        ((unsigned*)encH)[(base + p) * 32 + pr] =
            pkh(s[p * 65 + 2 * pr], s[p * 65 + 2 * pr + 1]);
    }
}

// ---------------------------------------------------------------------------
// k_deform R10: gather raw f16 corners directly in B-frag layout (as R9),
// blend on the INPUT side with packed v_pk_fma_f16 (32 pk-FMA/tap), then
// 8 accumulating MFMAs/tap (as R8). No LDS bounce, no unpack/repack, no
// zero-C restarts, no MFMA->VALU->acc chain.
// ---------------------------------------------------------------------------
#define REDW 20   // reduction row stride (floats): 80B, 16B-aligned

__global__ __launch_bounds__(256) void k_deform(
    const unsigned short* __restrict__ encH, const float* __restrict__ off,
    const float* __restrict__ msk, const short* __restrict__ wA,
    float* __restrict__ rev)
{
    __shared__ __align__(16) float red[2 * 64 * REDW]; // 10240 B reduction

    int t = threadIdx.x;
    int lane = t & 63, w = t >> 6;
    int b = blockIdx.x;
    int xcd = b & 7, blk = b >> 3;          // 288 strips per xcd band
    int gy  = xcd * 24 + blk / 12;
    int gx0 = (blk % 12) * 16;

    int n = lane & 15, q = lane >> 4;       // B-frag / C-frag lane mapping
    int sgx  = gx0 + n;
    int gp_s = gy * WW + sgx;

    f32x4 acc[4];
#pragma unroll
    for (int ot = 0; ot < 4; ot++) acc[ot] = (f32x4){0.f, 0.f, 0.f, 0.f};

    int kstart = (w == 0) ? 0 : 13 + (w - 1) * 12;
    int kend   = (w == 0) ? 13 : kstart + 12;

    float dy = off[(2 * kstart) * HWSZ + gp_s];
    float dx = off[(2 * kstart + 1) * HWSZ + gp_s];
    float mm = msk[kstart * HWSZ + gp_s];

    int ky = kstart / 7, kx = kstart % 7;

#pragma unroll 1
    for (int k = kstart; k < kend; k++) {
        float y = (float)(gy  - 3 + ky) + dy;
        float x = (float)(sgx - 3 + kx) + dx;
        float y0f = floorf(y), x0f = floorf(x);
        float wy = y - y0f, wx = x - x0f;
        int iy0 = (int)y0f, ix0 = (int)x0f;
        int iy1 = iy0 + 1, ix1 = ix0 + 1;
        bool vy0 = (iy0 >= 0) & (iy0 < HH);
        bool vy1 = (iy1 >= 0) & (iy1 < HH);
        bool vx0 = (ix0 >= 0) & (ix0 < WW);
        bool vx1 = (ix1 >= 0) & (ix1 < WW);
        int iy0c = min(max(iy0, 0), HH - 1), iy1c = min(max(iy1, 0), HH - 1);
        int ix0c = min(max(ix0, 0), WW - 1), ix1c = min(max(ix1, 0), WW - 1);
        float a00 = (vy0 & vx0) ? (1.f - wy) * (1.f - wx) * mm : 0.f;
        float a01 = (vy0 & vx1) ? (1.f - wy) * wx * mm : 0.f;
        float a10 = (vy1 & vx0) ? wy * (1.f - wx) * mm : 0.f;
        float a11 = (vy1 & vx1) ? wy * wx * mm : 0.f;

        // raw f16 corners, directly in B-frag layout: 2x16B per corner
        int r0 = iy0c * WW, r1 = iy1c * WW;
        const unsigned short* p00 = encH + ((r0 + ix0c) << 6) + (q << 3);
        const unsigned short* p01 = encH + ((r0 + ix1c) << 6) + (q << 3);
        const unsigned short* p10 = encH + ((r1 + ix0c) << 6) + (q << 3);
        const unsigned short* p11 = encH + ((r1 + ix1c) << 6) + (q << 3);
        uint4 u00a = *(const uint4*)p00, u00b = *(const uint4*)(p00 + 32);
        uint4 u01a = *(const uint4*)p01, u01b = *(const uint4*)(p01 + 32);
        uint4 u10a = *(const uint4*)p10, u10b = *(const uint4*)(p10 + 32);
        uint4 u11a = *(const uint4*)p11, u11b = *(const uint4*)(p11 + 32);

        // prefetch next-tap offsets
        float dyn = 0.f, dxn = 0.f, mmn = 0.f;
        if (k + 1 < kend) {
            dyn = off[(2 * k + 2) * HWSZ + gp_s];
            dxn = off[(2 * k + 3) * HWSZ + gp_s];
            mmn = msk[(k + 1) * HWSZ + gp_s];
        }

        // A-frag loads (L2-hot, independent of samples)
        h16x8 af[8];
#pragma unroll
        for (int f = 0; f < 8; f++)
            af[f] = *(const h16x8*)&wA[(k * 8 + f) * 512 + lane * 8];

        // packed-f16 bilinear blend in B-frag layout: 32 v_pk_fma_f16
        h16x2 w00 = cvt2h(a00);
        h16x2 w01 = cvt2h(a01);
        h16x2 w10 = cvt2h(a10);
        h16x2 w11 = cvt2h(a11);

        unsigned c00[8] = {u00a.x, u00a.y, u00a.z, u00a.w, u00b.x, u00b.y, u00b.z, u00b.w};
        unsigned c01[8] = {u01a.x, u01a.y, u01a.z, u01a.w, u01b.x, u01b.y, u01b.z, u01b.w};
        unsigned c10[8] = {u10a.x, u10a.y, u10a.z, u10a.w, u10b.x, u10b.y, u10b.z, u10b.w};
        unsigned c11[8] = {u11a.x, u11a.y, u11a.z, u11a.w, u11b.x, u11b.y, u11b.z, u11b.w};

        union { h16x8 v; h16x2 h[4]; } b0, b1;
#pragma unroll
        for (int j = 0; j < 4; j++) {
            h16x2 r = as_h2(c00[j]) * w00;
            r = as_h2(c01[j]) * w01 + r;
            r = as_h2(c10[j]) * w10 + r;
            r = as_h2(c11[j]) * w11 + r;
            b0.h[j] = r;
        }
#pragma unroll
        for (int j = 0; j < 4; j++) {
            h16x2 r = as_h2(c00[j + 4]) * w00;
            r = as_h2(c01[j + 4]) * w01 + r;
            r = as_h2(c10[j + 4]) * w10 + r;
            r = as_h2(c11[j + 4]) * w11 + r;
            b1.h[j] = r;
        }

#pragma unroll
        for (int ot = 0; ot < 4; ot++) {
            acc[ot] = __builtin_amdgcn_mfma_f32_16x16x32_f16(af[ot * 2],     b0.v, acc[ot], 0, 0, 0);
            acc[ot] = __builtin_amdgcn_mfma_f32_16x16x32_f16(af[ot * 2 + 1], b1.v, acc[ot], 0, 0, 0);
        }

        dy = dyn; dx = dxn; mm = mmn;
        kx++; if (kx == 7) { kx = 0; ky++; }
    }

    // two-phase tree reduction (2-slot buffer)
    if (w >= 2) {
        float* rp = &red[((w - 2) * 64 + lane) * REDW];
#pragma unroll
        for (int ot = 0; ot < 4; ot++)
            *(float4*)&rp[ot * 4] = make_float4(acc[ot][0], acc[ot][1], acc[ot][2], acc[ot][3]);
    }
    __syncthreads();
    if (w < 2) {
        const float* rp = &red[(w * 64 + lane) * REDW];
#pragma unroll
        for (int ot = 0; ot < 4; ot++) {
            float4 v = *(const float4*)&rp[ot * 4];
            acc[ot][0] += v.x; acc[ot][1] += v.y;
            acc[ot][2] += v.z; acc[ot][3] += v.w;
        }
    }
    __syncthreads();
    if (w == 1) {
        float* rp = &red[lane * REDW];
#pragma unroll
        for (int ot = 0; ot < 4; ot++)
            *(float4*)&rp[ot * 4] = make_float4(acc[ot][0], acc[ot][1], acc[ot][2], acc[ot][3]);
    }
    __syncthreads();
    if (w == 0) {
        const float* rp = &red[lane * REDW];
#pragma unroll
        for (int ot = 0; ot < 4; ot++) {
            float4 v = *(const float4*)&rp[ot * 4];
            acc[ot][0] += v.x; acc[ot][1] += v.y;
            acc[ot][2] += v.z; acc[ot][3] += v.w;
        }
        int gp_m = gy * WW + gx0 + n;
#pragma unroll
        for (int ot = 0; ot < 4; ot++) {
            float4 rv = make_float4(acc[ot][0], acc[ot][1], acc[ot][2], acc[ot][3]);
            *(float4*)&rev[gp_m * 64 + ot * 16 + q * 4] = rv;
        }
    }
}

// ---------------------------------------------------------------------------
// k_fft: per 8x8 patch: proj_in via MFMA f16, then circular conv (fp32).
// Stages straight from f16 encH (plain 16B copies, no packing).
// ---------------------------------------------------------------------------
__global__ __launch_bounds__(256) void k_fft(
    const unsigned short* __restrict__ encH, const short* __restrict__ wpiA,
    const float* __restrict__ krT, float* __restrict__ e1)
{
    __shared__ __align__(16) short sbf[64 * SROW];   // f16 enc [px][c]
    __shared__ __align__(16) float e0[64 * ROWP];    // fp32 [px][o]
    int t = threadIdx.x;
    int pbx = blockIdx.x % 24, pby = blockIdx.x / 24;
    int gx0 = pbx * 8, gy0 = pby * 8;

#pragma unroll
    for (int r = 0; r < 2; r++) {
        int idx = t + r * 256;             // 512 x 8-ch units
        int px = idx >> 3, g8 = idx & 7;
        int gy = gy0 + (px >> 3), gx = gx0 + (px & 7);
        *(uint4*)&sbf[px * SROW + g8 * 8] =
            *(const uint4*)&encH[(gy * WW + gx) * 64 + g8 * 8];
    }
    __syncthreads();

    int lane = t & 63, w = t >> 6;
    int n = lane & 15, q = lane >> 4;
    h16x8 a0 = *(const h16x8*)&wpiA[(w * 2 + 0) * 512 + lane * 8];
    h16x8 a1 = *(const h16x8*)&wpiA[(w * 2 + 1) * 512 + lane * 8];
#pragma unroll
    for (int j = 0; j < 4; j++) {
        h16x8 b0 = *(const h16x8*)&sbf[(j * 16 + n) * SROW +  0 + q * 8];
        h16x8 b1 = *(const h16x8*)&sbf[(j * 16 + n) * SROW + 32 + q * 8];
        f32x4 acc = {0.f, 0.f, 0.f, 0.f};
        acc = __builtin_amdgcn_mfma_f32_16x16x32_f16(a0, b0, acc, 0, 0, 0);
        acc = __builtin_amdgcn_mfma_f32_16x16x32_f16(a1, b1, acc, 0, 0, 0);
#pragma unroll
        for (int r = 0; r < 4; r++)
            e0[(j * 16 + n) * ROWP + w * 16 + q * 4 + r] = acc[r];
    }
    __syncthreads();

    int o = t & 63;
    int yb = t >> 6;
#pragma unroll
    for (int yy = 0; yy < 2; yy++) {
        int y = yb + yy * 4;
        float outr[8];
#pragma unroll
        for (int x = 0; x < 8; x++) outr[x] = 0.f;
#pragma unroll
        for (int u = 0; u < 8; u++) {
            int ry = (y - u + 8) & 7;
            float row[8];
#pragma unroll
            for (int rx = 0; rx < 8; rx++)
                row[rx] = e0[(ry * 8 + rx) * ROWP + o];
#pragma unroll
            for (int v = 0; v < 8; v++) {
                float kv = krT[(u * 8 + v) * 64 + o];
#pragma unroll
                for (int x = 0; x < 8; x++)
                    outr[x] += kv * row[(x - v + 8) & 7];
            }
        }
        int gy = gy0 + y;
#pragma unroll
        for (int x = 0; x < 8; x++)
            e1[(gy * WW + gx0 + x) * 64 + o] = outr[x];
    }
}

// ---------------------------------------------------------------------------
// k_c3out: fused conv3x3(e1+rev) -> [.,dec] -> proj_out -> SimpleGate.
// ---------------------------------------------------------------------------
__global__ __launch_bounds__(256) void k_c3out(
    const float* __restrict__ e1, const float* __restrict__ rev,
    const short* __restrict__ w2A, const float* __restrict__ dec,
    const short* __restrict__ wpoA, float* __restrict__ out)
{
    __shared__ __align__(16) short sm[4][54 * C3ROW];  // per-wave: 3 rows x 18 px
    int t = threadIdx.x;
    int lane = t & 63, w = t >> 6;
    int b = blockIdx.x;
    int xcd = b & 7, blk = b >> 3;
    int gy  = xcd * 24 + blk / 3;
    int gx0 = (blk % 3) * 64 + w * 16;
    short* smw = &sm[w][0];
    int n = lane & 15, q = lane >> 4;

    for (int r = 0; r < 14; r++) {
        int u = lane + r * 64;
        if (u < 864) {
            int rp = u >> 4, g = u & 15;
            int row = rp / 18, pxl = rp - row * 18;
            int gyy = gy + row - 1, gxx = gx0 + pxl - 1;
            float4 v = make_float4(0.f, 0.f, 0.f, 0.f);
            if (gyy >= 0 && gyy < HH && gxx >= 0 && gxx < WW) {
                int gp = (gyy * WW + gxx) * 64 + g * 4;
                float4 va = *(const float4*)&e1[gp];
                float4 vb = *(const float4*)&rev[gp];
                v.x = va.x + vb.x; v.y = va.y + vb.y;
                v.z = va.z + vb.z; v.w = va.w + vb.w;
            }
            *(uint2*)&smw[rp * C3ROW + g * 4] = make_uint2(pkh(v.x, v.y), pkh(v.z, v.w));
        }
    }

    f32x4 acc[4];
#pragma unroll
    for (int ot = 0; ot < 4; ot++) acc[ot] = (f32x4){0.f, 0.f, 0.f, 0.f};

#pragma unroll 1
    for (int tap = 0; tap < 9; tap++) {
        int dy = tap / 3, dx = tap - dy * 3;
        int rp = dy * 18 + n + dx;
        h16x8 b0 = *(const h16x8*)&smw[rp * C3ROW +  0 + q * 8];
        h16x8 b1 = *(const h16x8*)&smw[rp * C3ROW + 32 + q * 8];
#pragma unroll
        for (int ot = 0; ot < 4; ot++) {
            h16x8 a0 = *(const h16x8*)&w2A[(tap * 8 + ot * 2 + 0) * 512 + lane * 8];
            h16x8 a1 = *(const h16x8*)&w2A[(tap * 8 + ot * 2 + 1) * 512 + lane * 8];
            acc[ot] = __builtin_amdgcn_mfma_f32_16x16x32_f16(a0, b0, acc[ot], 0, 0, 0);
            acc[ot] = __builtin_amdgcn_mfma_f32_16x16x32_f16(a1, b1, acc[ot], 0, 0, 0);
        }
    }

    // fused proj_out: stage e3 (C-layout regs) + dec into B-frag rows
#pragma unroll
    for (int ot = 0; ot < 4; ot++) {
        unsigned lo = pkh(acc[ot][0], acc[ot][1]);
        unsigned hi = pkh(acc[ot][2], acc[ot][3]);
        *(uint2*)&smw[n * OROW + ot * 16 + q * 4] = make_uint2(lo, hi);
    }
    {
        int gp = gy * WW + gx0 + n;
        unsigned pk[8];
#pragma unroll
        for (int i = 0; i < 8; i++) {
            float va = dec[(q * 16 + 2 * i)     * HWSZ + gp];
            float vb = dec[(q * 16 + 2 * i + 1) * HWSZ + gp];
            pk[i] = pkh(va, vb);
        }
        *(uint4*)&smw[n * OROW + 64 + q * 16]     = make_uint4(pk[0], pk[1], pk[2], pk[3]);
        *(uint4*)&smw[n * OROW + 64 + q * 16 + 8] = make_uint4(pk[4], pk[5], pk[6], pk[7]);
    }

    f32x4 go[8];
#pragma unroll
    for (int ot = 0; ot < 8; ot++) go[ot] = (f32x4){0.f, 0.f, 0.f, 0.f};

#pragma unroll 1
    for (int kt = 0; kt < 4; kt++) {
        h16x8 bb = *(const h16x8*)&smw[n * OROW + kt * 32 + q * 8];
#pragma unroll
        for (int ot = 0; ot < 8; ot++) {
            h16x8 aa = *(const h16x8*)&wpoA[(ot * 4 + kt) * 512 + lane * 8];
            go[ot] = __builtin_amdgcn_mfma_f32_16x16x32_f16(aa, bb, go[ot], 0, 0, 0);
        }
    }

    int gp = gy * WW + gx0 + n;
#pragma unroll
    for (int ot = 0; ot < 4; ot++)
#pragma unroll
        for (int r = 0; r < 4; r++)
            out[(ot * 16 + q * 4 + r) * HWSZ + gp] = go[ot][r] * go[ot + 4][r];
}

// ---------------------------------------------------------------------------
extern "C" void kernel_launch(void* const* d_in, const int* in_sizes, int n_in,
                              void* d_out, int out_size, void* d_ws, size_t ws_size,
                              hipStream_t stream)
{
    const float* enc  = (const float*)d_in[0];
    const float* dec  = (const float*)d_in[1];
    const float* ioff = (const float*)d_in[2];
    const float* iwt  = (const float*)d_in[3];
    const float* wpi  = (const float*)d_in[4];
    const float* fw   = (const float*)d_in[5];
    const float* wpo  = (const float*)d_in[6];
    const float* wd   = (const float*)d_in[7];
    const float* wc1  = (const float*)d_in[8];
    const float* wc2  = (const float*)d_in[9];
    float* out = (float*)d_out;
    float* ws  = (float*)d_ws;

    float*          krT  = ws;                           //    4096
    float*          rev  = ws + 4096;                    // 2359296  [px][64]
    float*          e1   = ws + 2363392;                 // 2359296  [px][64]
    unsigned short* encH = (unsigned short*)(ws + 4722688); // 2359296 f16 (1179648 fl)
    short*          wA   = (short*)(ws + 5902336);       // 200704 f16
    short*          w2A  = (short*)(ws + 6002688);       //  36864 f16
    short*          wpoA = (short*)(ws + 6021120);       //  16384 f16
    short*          wpiA = (short*)(ws + 6029312);       //   4096 f16

    hipLaunchKernelGGL(k_prep,   dim3(49),   dim3(256), 0, stream,
                       fw, wd, wc2, wc1, wpo, wpi, krT, wA, w2A, wpoA, wpiA);
    hipLaunchKernelGGL(k_trans,  dim3(576),  dim3(256), 0, stream, enc, encH);
    hipLaunchKernelGGL(k_deform, dim3(2304), dim3(256), 0, stream, encH, ioff, iwt, wA, rev);
    hipLaunchKernelGGL(k_fft,    dim3(576),  dim3(256), 0, stream, encH, wpiA, krT, e1);
    hipLaunchKernelGGL(k_c3out,  dim3(576),  dim3(256), 0, stream, e1, rev, w2A, dec, wpoA, out);
}

// Round 4
// 270.386 us; speedup vs baseline: 1.0526x; 1.0155x over previous
//
#include <hip/hip_runtime.h>
#include <math.h>

#define CH    64
#define WW    192
#define HH    192
#define HWSZ  (192*192)
#define KK    49
#define ROWP  68   // padded fp32 LDS row (dwords)
#define SROW  72   // f16 row stride in shorts (144B)
#define C3ROW 72   // conv3 staged px stride (shorts)
#define OROW  136  // k_out staged px stride (shorts, 128ch + 8 pad)

typedef __attribute__((ext_vector_type(8))) short     s16x8;
typedef __attribute__((ext_vector_type(8))) _Float16  h16x8;  // 8 f16 = 4 VGPR
typedef __attribute__((ext_vector_type(2))) _Float16  h16x2;
typedef __attribute__((ext_vector_type(2))) __fp16    fp16x2; // cvt_pkrtz result type
typedef __attribute__((ext_vector_type(4))) float     f32x4;

__device__ __forceinline__ unsigned short f2h(float f) {
    union { _Float16 h; unsigned short s; } u; u.h = (_Float16)f;  // RNE
    return u.s;
}

// pack two floats to f16x2 (RTZ, single v_cvt_pkrtz_f16_f32)
__device__ __forceinline__ unsigned pkh(float lo, float hi) {
    union { fp16x2 h; unsigned u; } v;
    v.h = __builtin_amdgcn_cvt_pkrtz(lo, hi);
    return v.u;
}

// broadcast one float into packed f16x2 (for pk_fma weights)
__device__ __forceinline__ h16x2 cvt2h(float a) {
    union { fp16x2 h; h16x2 o; } v;
    v.h = __builtin_amdgcn_cvt_pkrtz(a, a);
    return v.o;
}

__device__ __forceinline__ h16x2 as_h2(unsigned u) {
    union { unsigned u; h16x2 h; } v; v.u = u; return v.h;
}

// ---------------------------------------------------------------------------
// k_prep (grid 49 x 256): krT + A-fragment packs (wA, w2A, wpoA, wpiA), f16
// ---------------------------------------------------------------------------
__device__ const float c_cos8[8] = {
    1.f, 0.70710678118654752f, 0.f, -0.70710678118654752f,
   -1.f, -0.70710678118654752f, 0.f, 0.70710678118654752f };

__global__ __launch_bounds__(256) void k_prep(
    const float* __restrict__ fw,   // [64,1,1,8,5]
    const float* __restrict__ wd,   // [64,64,7,7]
    const float* __restrict__ w2,   // [64,64,3,3]
    const float* __restrict__ wc1,  // [64,64,1,1]
    const float* __restrict__ wpo,  // [128,128]
    const float* __restrict__ wpi,  // [64,64]
    float* __restrict__ krT,        // [64 uv][64 c]
    short* __restrict__ wA,         // [49*8*512]
    short* __restrict__ w2A,        // [9*8*512]
    short* __restrict__ wpoA,       // [32*512]
    short* __restrict__ wpiA)       // [8*512]
{
    int tid = blockIdx.x * blockDim.x + threadIdx.x;
    int nt  = gridDim.x * blockDim.x;
    for (int t = tid; t < 64 * 64; t += nt) {
        int uv = t >> 6, c = t & 63;
        int u = uv >> 3, v = uv & 7;
        float acc = 0.f;
        for (int ky = 0; ky < 8; ky++)
            for (int kx = 0; kx < 8; kx++) {
                float wv = (kx <= 4) ? fw[c * 40 + ky * 5 + kx]
                                     : fw[c * 40 + ((8 - ky) & 7) * 5 + (8 - kx)];
                acc += wv * c_cos8[(ky * u + kx * v) & 7];
            }
        krT[uv * 64 + c] = acc * (1.f / 64.f);
    }
    for (int t = tid; t < 9 * 4096; t += nt) {
        int tap = t / 4096, rem = t & 4095;
        int o = rem >> 6, c = rem & 63;
        float v = w2[(o * 64 + c) * 9 + tap];
        int fi = tap * 8 + (o >> 4) * 2 + (c >> 5);
        int ln = ((c >> 3) & 3) * 16 + (o & 15);
        w2A[fi * 512 + ln * 8 + (c & 7)] = (short)f2h(v);
    }
    for (int t = tid; t < 128 * 128; t += nt) {
        int o = t >> 7, c = t & 127;
        int fi = (o >> 4) * 4 + (c >> 5);
        int ln = ((c >> 3) & 3) * 16 + (o & 15);
        wpoA[fi * 512 + ln * 8 + (c & 7)] = (short)f2h(wpo[t]);
    }
    for (int t = tid; t < 64 * 64; t += nt) {
        int o = t >> 6, c = t & 63;
        int fi = (o >> 4) * 2 + (c >> 5);
        int ln = ((c >> 3) & 3) * 16 + (o & 15);
        wpiA[fi * 512 + ln * 8 + (c & 7)] = (short)f2h(wpi[t]);
    }

    // ---- fold wc1 @ wd + pack: one block per tap k ----
    __shared__ float wdk [64 * ROWP];
    __shared__ float wc1s[64 * ROWP];
    int k = blockIdx.x;
    int t = threadIdx.x;
#pragma unroll
    for (int r = 0; r < 16; r++) {
        int idx = t + r * 256;
        int o = idx >> 6, c = idx & 63;
        wdk [o * ROWP + c] = wd[(o * 64 + c) * KK + k];
        wc1s[o * ROWP + c] = wc1[o * 64 + c];
    }
    __syncthreads();

    int ot = (t >> 4) * 4, cb = (t & 15) * 4;
    float a[4][4];
#pragma unroll
    for (int i = 0; i < 4; i++)
#pragma unroll
        for (int j = 0; j < 4; j++) a[i][j] = 0.f;
    for (int o = 0; o < 64; o++) {
        float wv_[4], sv_[4];
#pragma unroll
        for (int i = 0; i < 4; i++) wv_[i] = wc1s[(ot + i) * ROWP + o];
#pragma unroll
        for (int j = 0; j < 4; j++) sv_[j] = wdk[o * ROWP + cb + j];
#pragma unroll
        for (int i = 0; i < 4; i++)
#pragma unroll
            for (int j = 0; j < 4; j++) a[i][j] += wv_[i] * sv_[j];
    }
#pragma unroll
    for (int i = 0; i < 4; i++)
#pragma unroll
        for (int j = 0; j < 4; j++) {
            int o2 = ot + i, c = cb + j;
            int tt = o2 >> 4, m = o2 & 15;
            int kt = c >> 5, q = (c >> 3) & 3, jj = c & 7;
            int ln = q * 16 + m;
            wA[(k * 8 + tt * 2 + kt) * 512 + ln * 8 + jj] = (short)f2h(a[i][j]);
        }
}

// ---------------------------------------------------------------------------
// k_trans: enc [c][p] (fp32) -> encH [p][c] (f16) -- halves gather bytes
// ---------------------------------------------------------------------------
__global__ __launch_bounds__(256) void k_trans(
    const float* __restrict__ enc, unsigned short* __restrict__ encH)
{
    __shared__ float s[64 * 65];
    int t = threadIdx.x;
    int base = blockIdx.x * 64;
#pragma unroll
    for (int r = 0; r < 16; r++) {
        int idx = t + r * 256;
        int p = idx & 63, c = idx >> 6;
        s[p * 65 + c] = enc[c * HWSZ + base + p];
    }
    __syncthreads();
#pragma unroll
    for (int r = 0; r < 8; r++) {
        int idx = t + r * 256;             // 2048 pair-units
        int pr = idx & 31, p = idx >> 5;   // pair 0..31, px 0..63
        ((unsigned*)encH)[(base + p) * 32 + pr] =
            pkh(s[p * 65 + 2 * pr], s[p * 65 + 2 * pr + 1]);
    }
}

// ---------------------------------------------------------------------------
// k_deform R11: R10's packed-f16 input blend + MLP fix. Taps processed in
// PAIRS (4 waves x 12 taps + tap48 peeled to wave0): 16 corner loads issued
// at iteration top before any use -> 2x outstanding VMEM, tap-A compute
// covers tap-B load latency. Offset prefetch one pair ahead.
// ---------------------------------------------------------------------------
#define REDW 20   // reduction row stride (floats): 80B, 16B-aligned

__device__ __forceinline__ void tap_setup(
    int k, int gy, int sgx, float dy, float dx, float mm,
    const unsigned short* __restrict__ encH, int q,
    float& a00, float& a01, float& a10, float& a11,
    const unsigned short*& p00, const unsigned short*& p01,
    const unsigned short*& p10, const unsigned short*& p11)
{
    int ky = k / 7, kx = k % 7;
    float y = (float)(gy  - 3 + ky) + dy;
    float x = (float)(sgx - 3 + kx) + dx;
    float y0f = floorf(y), x0f = floorf(x);
    float wy = y - y0f, wx = x - x0f;
    int iy0 = (int)y0f, ix0 = (int)x0f;
    int iy1 = iy0 + 1, ix1 = ix0 + 1;
    bool vy0 = (iy0 >= 0) & (iy0 < HH);
    bool vy1 = (iy1 >= 0) & (iy1 < HH);
    bool vx0 = (ix0 >= 0) & (ix0 < WW);
    bool vx1 = (ix1 >= 0) & (ix1 < WW);
    int iy0c = min(max(iy0, 0), HH - 1), iy1c = min(max(iy1, 0), HH - 1);
    int ix0c = min(max(ix0, 0), WW - 1), ix1c = min(max(ix1, 0), WW - 1);
    a00 = (vy0 & vx0) ? (1.f - wy) * (1.f - wx) * mm : 0.f;
    a01 = (vy0 & vx1) ? (1.f - wy) * wx * mm : 0.f;
    a10 = (vy1 & vx0) ? wy * (1.f - wx) * mm : 0.f;
    a11 = (vy1 & vx1) ? wy * wx * mm : 0.f;
    int r0 = iy0c * WW, r1 = iy1c * WW;
    p00 = encH + ((r0 + ix0c) << 6) + (q << 3);
    p01 = encH + ((r0 + ix1c) << 6) + (q << 3);
    p10 = encH + ((r1 + ix0c) << 6) + (q << 3);
    p11 = encH + ((r1 + ix1c) << 6) + (q << 3);
}

__device__ __forceinline__ void tap_blend_mfma(
    const uint4& u00a, const uint4& u00b, const uint4& u01a, const uint4& u01b,
    const uint4& u10a, const uint4& u10b, const uint4& u11a, const uint4& u11b,
    float a00, float a01, float a10, float a11,
    const short* __restrict__ wAk, f32x4 (&acc)[4])
{
    h16x2 w00 = cvt2h(a00);
    h16x2 w01 = cvt2h(a01);
    h16x2 w10 = cvt2h(a10);
    h16x2 w11 = cvt2h(a11);

    unsigned c00[8] = {u00a.x, u00a.y, u00a.z, u00a.w, u00b.x, u00b.y, u00b.z, u00b.w};
    unsigned c01[8] = {u01a.x, u01a.y, u01a.z, u01a.w, u01b.x, u01b.y, u01b.z, u01b.w};
    unsigned c10[8] = {u10a.x, u10a.y, u10a.z, u10a.w, u10b.x, u10b.y, u10b.z, u10b.w};
    unsigned c11[8] = {u11a.x, u11a.y, u11a.z, u11a.w, u11b.x, u11b.y, u11b.z, u11b.w};

    union { h16x8 v; h16x2 h[4]; } b0, b1;
#pragma unroll
    for (int j = 0; j < 4; j++) {
        h16x2 r = as_h2(c00[j]) * w00;
        r = as_h2(c01[j]) * w01 + r;
        r = as_h2(c10[j]) * w10 + r;
        r = as_h2(c11[j]) * w11 + r;
        b0.h[j] = r;
    }
#pragma unroll
    for (int j = 0; j < 4; j++) {
        h16x2 r = as_h2(c00[j + 4]) * w00;
        r = as_h2(c01[j + 4]) * w01 + r;
        r = as_h2(c10[j + 4]) * w10 + r;
        r = as_h2(c11[j + 4]) * w11 + r;
        b1.h[j] = r;
    }

#pragma unroll
    for (int ot = 0; ot < 4; ot++) {
        h16x8 af0 = *(const h16x8*)&wAk[(ot * 2 + 0) * 512];
        h16x8 af1 = *(const h16x8*)&wAk[(ot * 2 + 1) * 512];
        acc[ot] = __builtin_amdgcn_mfma_f32_16x16x32_f16(af0, b0.v, acc[ot], 0, 0, 0);
        acc[ot] = __builtin_amdgcn_mfma_f32_16x16x32_f16(af1, b1.v, acc[ot], 0, 0, 0);
    }
}

__global__ __launch_bounds__(256) void k_deform(
    const unsigned short* __restrict__ encH, const float* __restrict__ off,
    const float* __restrict__ msk, const short* __restrict__ wA,
    float* __restrict__ rev)
{
    __shared__ __align__(16) float red[2 * 64 * REDW]; // 10240 B reduction

    int t = threadIdx.x;
    int lane = t & 63, w = t >> 6;
    int b = blockIdx.x;
    int xcd = b & 7, blk = b >> 3;          // 288 strips per xcd band
    int gy  = xcd * 24 + blk / 12;
    int gx0 = (blk % 12) * 16;

    int n = lane & 15, q = lane >> 4;       // B-frag / C-frag lane mapping
    int sgx  = gx0 + n;
    int gp_s = gy * WW + sgx;

    f32x4 acc[4];
#pragma unroll
    for (int ot = 0; ot < 4; ot++) acc[ot] = (f32x4){0.f, 0.f, 0.f, 0.f};

    int base0 = w * 12;                     // taps [base0, base0+12); w0 also does 48

    // offsets for pair 0
    float dyA = off[(2 * base0)     * HWSZ + gp_s];
    float dxA = off[(2 * base0 + 1) * HWSZ + gp_s];
    float mmA = msk[ base0          * HWSZ + gp_s];
    float dyB = off[(2 * base0 + 2) * HWSZ + gp_s];
    float dxB = off[(2 * base0 + 3) * HWSZ + gp_s];
    float mmB = msk[(base0 + 1)     * HWSZ + gp_s];

#pragma unroll 1
    for (int kp = base0; kp < base0 + 12; kp += 2) {
        int ka = kp, kb = kp + 1;

        float aA00, aA01, aA10, aA11, aB00, aB01, aB10, aB11;
        const unsigned short *pA00, *pA01, *pA10, *pA11;
        const unsigned short *pB00, *pB01, *pB10, *pB11;
        tap_setup(ka, gy, sgx, dyA, dxA, mmA, encH, q, aA00, aA01, aA10, aA11,
                  pA00, pA01, pA10, pA11);
        tap_setup(kb, gy, sgx, dyB, dxB, mmB, encH, q, aB00, aB01, aB10, aB11,
                  pB00, pB01, pB10, pB11);

        // issue all 16 corner loads before any consumption
        uint4 uA00a = *(const uint4*)pA00, uA00b = *(const uint4*)(pA00 + 32);
        uint4 uA01a = *(const uint4*)pA01, uA01b = *(const uint4*)(pA01 + 32);
        uint4 uA10a = *(const uint4*)pA10, uA10b = *(const uint4*)(pA10 + 32);
        uint4 uA11a = *(const uint4*)pA11, uA11b = *(const uint4*)(pA11 + 32);
        uint4 uB00a = *(const uint4*)pB00, uB00b = *(const uint4*)(pB00 + 32);
        uint4 uB01a = *(const uint4*)pB01, uB01b = *(const uint4*)(pB01 + 32);
        uint4 uB10a = *(const uint4*)pB10, uB10b = *(const uint4*)(pB10 + 32);
        uint4 uB11a = *(const uint4*)pB11, uB11b = *(const uint4*)(pB11 + 32);

        // prefetch offsets for next pair (clamped; values unused on last iter)
        int kn = (kp + 2 < base0 + 12) ? kp + 2 : base0;
        dyA = off[(2 * kn)     * HWSZ + gp_s];
        dxA = off[(2 * kn + 1) * HWSZ + gp_s];
        mmA = msk[ kn          * HWSZ + gp_s];
        dyB = off[(2 * kn + 2) * HWSZ + gp_s];
        dxB = off[(2 * kn + 3) * HWSZ + gp_s];
        mmB = msk[(kn + 1)     * HWSZ + gp_s];

        tap_blend_mfma(uA00a, uA00b, uA01a, uA01b, uA10a, uA10b, uA11a, uA11b,
                       aA00, aA01, aA10, aA11, &wA[ka * 8 * 512 + lane * 8], acc);
        tap_blend_mfma(uB00a, uB00b, uB01a, uB01b, uB10a, uB10b, uB11a, uB11b,
                       aB00, aB01, aB10, aB11, &wA[kb * 8 * 512 + lane * 8], acc);
    }

    // peeled tap 48 (wave 0 only)
    if (w == 0) {
        int k = 48;
        float dy = off[(2 * k) * HWSZ + gp_s];
        float dx = off[(2 * k + 1) * HWSZ + gp_s];
        float mm = msk[k * HWSZ + gp_s];
        float a00, a01, a10, a11;
        const unsigned short *p00, *p01, *p10, *p11;
        tap_setup(k, gy, sgx, dy, dx, mm, encH, q, a00, a01, a10, a11,
                  p00, p01, p10, p11);
        uint4 u00a = *(const uint4*)p00, u00b = *(const uint4*)(p00 + 32);
        uint4 u01a = *(const uint4*)p01, u01b = *(const uint4*)(p01 + 32);
        uint4 u10a = *(const uint4*)p10, u10b = *(const uint4*)(p10 + 32);
        uint4 u11a = *(const uint4*)p11, u11b = *(const uint4*)(p11 + 32);
        tap_blend_mfma(u00a, u00b, u01a, u01b, u10a, u10b, u11a, u11b,
                       a00, a01, a10, a11, &wA[k * 8 * 512 + lane * 8], acc);
    }

    // two-phase tree reduction (2-slot buffer)
    if (w >= 2) {
        float* rp = &red[((w - 2) * 64 + lane) * REDW];
#pragma unroll
        for (int ot = 0; ot < 4; ot++)
            *(float4*)&rp[ot * 4] = make_float4(acc[ot][0], acc[ot][1], acc[ot][2], acc[ot][3]);
    }
    __syncthreads();
    if (w < 2) {
        const float* rp = &red[(w * 64 + lane) * REDW];
#pragma unroll
        for (int ot = 0; ot < 4; ot++) {
            float4 v = *(const float4*)&rp[ot * 4];
            acc[ot][0] += v.x; acc[ot][1] += v.y;
            acc[ot][2] += v.z; acc[ot][3] += v.w;
        }
    }
    __syncthreads();
    if (w == 1) {
        float* rp = &red[lane * REDW];
#pragma unroll
        for (int ot = 0; ot < 4; ot++)
            *(float4*)&rp[ot * 4] = make_float4(acc[ot][0], acc[ot][1], acc[ot][2], acc[ot][3]);
    }
    __syncthreads();
    if (w == 0) {
        const float* rp = &red[lane * REDW];
#pragma unroll
        for (int ot = 0; ot < 4; ot++) {
            float4 v = *(const float4*)&rp[ot * 4];
            acc[ot][0] += v.x; acc[ot][1] += v.y;
            acc[ot][2] += v.z; acc[ot][3] += v.w;
        }
        int gp_m = gy * WW + gx0 + n;
#pragma unroll
        for (int ot = 0; ot < 4; ot++) {
            float4 rv = make_float4(acc[ot][0], acc[ot][1], acc[ot][2], acc[ot][3]);
            *(float4*)&rev[gp_m * 64 + ot * 16 + q * 4] = rv;
        }
    }
}

// ---------------------------------------------------------------------------
// k_fft: per 8x8 patch: proj_in via MFMA f16, then circular conv (fp32).
// Stages straight from f16 encH (plain 16B copies, no packing).
// ---------------------------------------------------------------------------
__global__ __launch_bounds__(256) void k_fft(
    const unsigned short* __restrict__ encH, const short* __restrict__ wpiA,
    const float* __restrict__ krT, float* __restrict__ e1)
{
    __shared__ __align__(16) short sbf[64 * SROW];   // f16 enc [px][c]
    __shared__ __align__(16) float e0[64 * ROWP];    // fp32 [px][o]
    int t = threadIdx.x;
    int pbx = blockIdx.x % 24, pby = blockIdx.x / 24;
    int gx0 = pbx * 8, gy0 = pby * 8;

#pragma unroll
    for (int r = 0; r < 2; r++) {
        int idx = t + r * 256;             // 512 x 8-ch units
        int px = idx >> 3, g8 = idx & 7;
        int gy = gy0 + (px >> 3), gx = gx0 + (px & 7);
        *(uint4*)&sbf[px * SROW + g8 * 8] =
            *(const uint4*)&encH[(gy * WW + gx) * 64 + g8 * 8];
    }
    __syncthreads();

    int lane = t & 63, w = t >> 6;
    int n = lane & 15, q = lane >> 4;
    h16x8 a0 = *(const h16x8*)&wpiA[(w * 2 + 0) * 512 + lane * 8];
    h16x8 a1 = *(const h16x8*)&wpiA[(w * 2 + 1) * 512 + lane * 8];
#pragma unroll
    for (int j = 0; j < 4; j++) {
        h16x8 b0 = *(const h16x8*)&sbf[(j * 16 + n) * SROW +  0 + q * 8];
        h16x8 b1 = *(const h16x8*)&sbf[(j * 16 + n) * SROW + 32 + q * 8];
        f32x4 acc = {0.f, 0.f, 0.f, 0.f};
        acc = __builtin_amdgcn_mfma_f32_16x16x32_f16(a0, b0, acc, 0, 0, 0);
        acc = __builtin_amdgcn_mfma_f32_16x16x32_f16(a1, b1, acc, 0, 0, 0);
#pragma unroll
        for (int r = 0; r < 4; r++)
            e0[(j * 16 + n) * ROWP + w * 16 + q * 4 + r] = acc[r];
    }
    __syncthreads();

    int o = t & 63;
    int yb = t >> 6;
#pragma unroll
    for (int yy = 0; yy < 2; yy++) {
        int y = yb + yy * 4;
        float outr[8];
#pragma unroll
        for (int x = 0; x < 8; x++) outr[x] = 0.f;
#pragma unroll
        for (int u = 0; u < 8; u++) {
            int ry = (y - u + 8) & 7;
            float row[8];
#pragma unroll
            for (int rx = 0; rx < 8; rx++)
                row[rx] = e0[(ry * 8 + rx) * ROWP + o];
#pragma unroll
            for (int v = 0; v < 8; v++) {
                float kv = krT[(u * 8 + v) * 64 + o];
#pragma unroll
                for (int x = 0; x < 8; x++)
                    outr[x] += kv * row[(x - v + 8) & 7];
            }
        }
        int gy = gy0 + y;
#pragma unroll
        for (int x = 0; x < 8; x++)
            e1[(gy * WW + gx0 + x) * 64 + o] = outr[x];
    }
}

// ---------------------------------------------------------------------------
// k_c3out: fused conv3x3(e1+rev) -> [.,dec] -> proj_out -> SimpleGate.
// ---------------------------------------------------------------------------
__global__ __launch_bounds__(256) void k_c3out(
    const float* __restrict__ e1, const float* __restrict__ rev,
    const short* __restrict__ w2A, const float* __restrict__ dec,
    const short* __restrict__ wpoA, float* __restrict__ out)
{
    __shared__ __align__(16) short sm[4][54 * C3ROW];  // per-wave: 3 rows x 18 px
    int t = threadIdx.x;
    int lane = t & 63, w = t >> 6;
    int b = blockIdx.x;
    int xcd = b & 7, blk = b >> 3;
    int gy  = xcd * 24 + blk / 3;
    int gx0 = (blk % 3) * 64 + w * 16;
    short* smw = &sm[w][0];
    int n = lane & 15, q = lane >> 4;

    for (int r = 0; r < 14; r++) {
        int u = lane + r * 64;
        if (u < 864) {
            int rp = u >> 4, g = u & 15;
            int row = rp / 18, pxl = rp - row * 18;
            int gyy = gy + row - 1, gxx = gx0 + pxl - 1;
            float4 v = make_float4(0.f, 0.f, 0.f, 0.f);
            if (gyy >= 0 && gyy < HH && gxx >= 0 && gxx < WW) {
                int gp = (gyy * WW + gxx) * 64 + g * 4;
                float4 va = *(const float4*)&e1[gp];
                float4 vb = *(const float4*)&rev[gp];
                v.x = va.x + vb.x; v.y = va.y + vb.y;
                v.z = va.z + vb.z; v.w = va.w + vb.w;
            }
            *(uint2*)&smw[rp * C3ROW + g * 4] = make_uint2(pkh(v.x, v.y), pkh(v.z, v.w));
        }
    }

    f32x4 acc[4];
#pragma unroll
    for (int ot = 0; ot < 4; ot++) acc[ot] = (f32x4){0.f, 0.f, 0.f, 0.f};

#pragma unroll 1
    for (int tap = 0; tap < 9; tap++) {
        int dy = tap / 3, dx = tap - dy * 3;
        int rp = dy * 18 + n + dx;
        h16x8 b0 = *(const h16x8*)&smw[rp * C3ROW +  0 + q * 8];
        h16x8 b1 = *(const h16x8*)&smw[rp * C3ROW + 32 + q * 8];
#pragma unroll
        for (int ot = 0; ot < 4; ot++) {
            h16x8 a0 = *(const h16x8*)&w2A[(tap * 8 + ot * 2 + 0) * 512 + lane * 8];
            h16x8 a1 = *(const h16x8*)&w2A[(tap * 8 + ot * 2 + 1) * 512 + lane * 8];
            acc[ot] = __builtin_amdgcn_mfma_f32_16x16x32_f16(a0, b0, acc[ot], 0, 0, 0);
            acc[ot] = __builtin_amdgcn_mfma_f32_16x16x32_f16(a1, b1, acc[ot], 0, 0, 0);
        }
    }

    // fused proj_out: stage e3 (C-layout regs) + dec into B-frag rows
#pragma unroll
    for (int ot = 0; ot < 4; ot++) {
        unsigned lo = pkh(acc[ot][0], acc[ot][1]);
        unsigned hi = pkh(acc[ot][2], acc[ot][3]);
        *(uint2*)&smw[n * OROW + ot * 16 + q * 4] = make_uint2(lo, hi);
    }
    {
        int gp = gy * WW + gx0 + n;
        unsigned pk[8];
#pragma unroll
        for (int i = 0; i < 8; i++) {
            float va = dec[(q * 16 + 2 * i)     * HWSZ + gp];
            float vb = dec[(q * 16 + 2 * i + 1) * HWSZ + gp];
            pk[i] = pkh(va, vb);
        }
        *(uint4*)&smw[n * OROW + 64 + q * 16]     = make_uint4(pk[0], pk[1], pk[2], pk[3]);
        *(uint4*)&smw[n * OROW + 64 + q * 16 + 8] = make_uint4(pk[4], pk[5], pk[6], pk[7]);
    }

    f32x4 go[8];
#pragma unroll
    for (int ot = 0; ot < 8; ot++) go[ot] = (f32x4){0.f, 0.f, 0.f, 0.f};

#pragma unroll 1
    for (int kt = 0; kt < 4; kt++) {
        h16x8 bb = *(const h16x8*)&smw[n * OROW + kt * 32 + q * 8];
#pragma unroll
        for (int ot = 0; ot < 8; ot++) {
            h16x8 aa = *(const h16x8*)&wpoA[(ot * 4 + kt) * 512 + lane * 8];
            go[ot] = __builtin_amdgcn_mfma_f32_16x16x32_f16(aa, bb, go[ot], 0, 0, 0);
        }
    }

    int gp = gy * WW + gx0 + n;
#pragma unroll
    for (int ot = 0; ot < 4; ot++)
#pragma unroll
        for (int r = 0; r < 4; r++)
            out[(ot * 16 + q * 4 + r) * HWSZ + gp] = go[ot][r] * go[ot + 4][r];
}

// ---------------------------------------------------------------------------
extern "C" void kernel_launch(void* const* d_in, const int* in_sizes, int n_in,
                              void* d_out, int out_size, void* d_ws, size_t ws_size,
                              hipStream_t stream)
{
    const float* enc  = (const float*)d_in[0];
    const float* dec  = (const float*)d_in[1];
    const float* ioff = (const float*)d_in[2];
    const float* iwt  = (const float*)d_in[3];
    const float* wpi  = (const float*)d_in[4];
    const float* fw   = (const float*)d_in[5];
    const float* wpo  = (const float*)d_in[6];
    const float* wd   = (const float*)d_in[7];
    const float* wc1  = (const float*)d_in[8];
    const float* wc2  = (const float*)d_in[9];
    float* out = (float*)d_out;
    float* ws  = (float*)d_ws;

    float*          krT  = ws;                           //    4096
    float*          rev  = ws + 4096;                    // 2359296  [px][64]
    float*          e1   = ws + 2363392;                 // 2359296  [px][64]
    unsigned short* encH = (unsigned short*)(ws + 4722688); // 2359296 f16 (1179648 fl)
    short*          wA   = (short*)(ws + 5902336);       // 200704 f16
    short*          w2A  = (short*)(ws + 6002688);       //  36864 f16
    short*          wpoA = (short*)(ws + 6021120);       //  16384 f16
    short*          wpiA = (short*)(ws + 6029312);       //   4096 f16

    hipLaunchKernelGGL(k_prep,   dim3(49),   dim3(256), 0, stream,
                       fw, wd, wc2, wc1, wpo, wpi, krT, wA, w2A, wpoA, wpiA);
    hipLaunchKernelGGL(k_trans,  dim3(576),  dim3(256), 0, stream, enc, encH);
    hipLaunchKernelGGL(k_deform, dim3(2304), dim3(256), 0, stream, encH, ioff, iwt, wA, rev);
    hipLaunchKernelGGL(k_fft,    dim3(576),  dim3(256), 0, stream, encH, wpiA, krT, e1);
    hipLaunchKernelGGL(k_c3out,  dim3(576),  dim3(256), 0, stream, e1, rev, w2A, dec, wpoA, out);
}

// Round 5
// 214.054 us; speedup vs baseline: 1.3296x; 1.2632x over previous
//
#include <hip/hip_runtime.h>
#include <math.h>

#define CH    64
#define WW    192
#define HH    192
#define HWSZ  (192*192)
#define KK    49
#define ROWP  68   // padded fp32 LDS row (dwords)
#define SROW  72   // f16 row stride in shorts (144B)
#define C3ROW 72   // conv3 staged px stride (shorts)
#define OROW  136  // k_out staged px stride (shorts, 128ch + 8 pad)

typedef __attribute__((ext_vector_type(8))) short     s16x8;
typedef __attribute__((ext_vector_type(8))) _Float16  h16x8;  // 8 f16 = 4 VGPR
typedef __attribute__((ext_vector_type(2))) _Float16  h16x2;
typedef __attribute__((ext_vector_type(2))) __fp16    fp16x2; // cvt_pkrtz result type
typedef __attribute__((ext_vector_type(4))) float     f32x4;

__device__ __forceinline__ unsigned short f2h(float f) {
    union { _Float16 h; unsigned short s; } u; u.h = (_Float16)f;  // RNE
    return u.s;
}

// pack two floats to f16x2 (RTZ, single v_cvt_pkrtz_f16_f32)
__device__ __forceinline__ unsigned pkh(float lo, float hi) {
    union { fp16x2 h; unsigned u; } v;
    v.h = __builtin_amdgcn_cvt_pkrtz(lo, hi);
    return v.u;
}

// broadcast one float into packed f16x2 (for pk_fma weights)
__device__ __forceinline__ h16x2 cvt2h(float a) {
    union { fp16x2 h; h16x2 o; } v;
    v.h = __builtin_amdgcn_cvt_pkrtz(a, a);
    return v.o;
}

__device__ __forceinline__ h16x2 as_h2(unsigned u) {
    union { unsigned u; h16x2 h; } v; v.u = u; return v.h;
}

__device__ __forceinline__ unsigned as_u(h16x2 h) {
    union { h16x2 h; unsigned u; } v; v.h = h; return v.u;
}

// ---------------------------------------------------------------------------
// k_prep (grid 49 x 256): krT + A-fragment packs (wA, w2A, wpoA, wpiA), f16
// ---------------------------------------------------------------------------
__device__ const float c_cos8[8] = {
    1.f, 0.70710678118654752f, 0.f, -0.70710678118654752f,
   -1.f, -0.70710678118654752f, 0.f, 0.70710678118654752f };

__global__ __launch_bounds__(256) void k_prep(
    const float* __restrict__ fw,   // [64,1,1,8,5]
    const float* __restrict__ wd,   // [64,64,7,7]
    const float* __restrict__ w2,   // [64,64,3,3]
    const float* __restrict__ wc1,  // [64,64,1,1]
    const float* __restrict__ wpo,  // [128,128]
    const float* __restrict__ wpi,  // [64,64]
    float* __restrict__ krT,        // [64 uv][64 c]
    short* __restrict__ wA,         // [49*8*512]
    short* __restrict__ w2A,        // [9*8*512]
    short* __restrict__ wpoA,       // [32*512]
    short* __restrict__ wpiA)       // [8*512]
{
    int tid = blockIdx.x * blockDim.x + threadIdx.x;
    int nt  = gridDim.x * blockDim.x;
    for (int t = tid; t < 64 * 64; t += nt) {
        int uv = t >> 6, c = t & 63;
        int u = uv >> 3, v = uv & 7;
        float acc = 0.f;
        for (int ky = 0; ky < 8; ky++)
            for (int kx = 0; kx < 8; kx++) {
                float wv = (kx <= 4) ? fw[c * 40 + ky * 5 + kx]
                                     : fw[c * 40 + ((8 - ky) & 7) * 5 + (8 - kx)];
                acc += wv * c_cos8[(ky * u + kx * v) & 7];
            }
        krT[uv * 64 + c] = acc * (1.f / 64.f);
    }
    for (int t = tid; t < 9 * 4096; t += nt) {
        int tap = t / 4096, rem = t & 4095;
        int o = rem >> 6, c = rem & 63;
        float v = w2[(o * 64 + c) * 9 + tap];
        int fi = tap * 8 + (o >> 4) * 2 + (c >> 5);
        int ln = ((c >> 3) & 3) * 16 + (o & 15);
        w2A[fi * 512 + ln * 8 + (c & 7)] = (short)f2h(v);
    }
    for (int t = tid; t < 128 * 128; t += nt) {
        int o = t >> 7, c = t & 127;
        int fi = (o >> 4) * 4 + (c >> 5);
        int ln = ((c >> 3) & 3) * 16 + (o & 15);
        wpoA[fi * 512 + ln * 8 + (c & 7)] = (short)f2h(wpo[t]);
    }
    for (int t = tid; t < 64 * 64; t += nt) {
        int o = t >> 6, c = t & 63;
        int fi = (o >> 4) * 2 + (c >> 5);
        int ln = ((c >> 3) & 3) * 16 + (o & 15);
        wpiA[fi * 512 + ln * 8 + (c & 7)] = (short)f2h(wpi[t]);
    }

    // ---- fold wc1 @ wd + pack: one block per tap k ----
    __shared__ float wdk [64 * ROWP];
    __shared__ float wc1s[64 * ROWP];
    int k = blockIdx.x;
    int t = threadIdx.x;
#pragma unroll
    for (int r = 0; r < 16; r++) {
        int idx = t + r * 256;
        int o = idx >> 6, c = idx & 63;
        wdk [o * ROWP + c] = wd[(o * 64 + c) * KK + k];
        wc1s[o * ROWP + c] = wc1[o * 64 + c];
    }
    __syncthreads();

    int ot = (t >> 4) * 4, cb = (t & 15) * 4;
    float a[4][4];
#pragma unroll
    for (int i = 0; i < 4; i++)
#pragma unroll
        for (int j = 0; j < 4; j++) a[i][j] = 0.f;
    for (int o = 0; o < 64; o++) {
        float wv_[4], sv_[4];
#pragma unroll
        for (int i = 0; i < 4; i++) wv_[i] = wc1s[(ot + i) * ROWP + o];
#pragma unroll
        for (int j = 0; j < 4; j++) sv_[j] = wdk[o * ROWP + cb + j];
#pragma unroll
        for (int i = 0; i < 4; i++)
#pragma unroll
            for (int j = 0; j < 4; j++) a[i][j] += wv_[i] * sv_[j];
    }
#pragma unroll
    for (int i = 0; i < 4; i++)
#pragma unroll
        for (int j = 0; j < 4; j++) {
            int o2 = ot + i, c = cb + j;
            int tt = o2 >> 4, m = o2 & 15;
            int kt = c >> 5, q = (c >> 3) & 3, jj = c & 7;
            int ln = q * 16 + m;
            wA[(k * 8 + tt * 2 + kt) * 512 + ln * 8 + jj] = (short)f2h(a[i][j]);
        }
}

// ---------------------------------------------------------------------------
// k_trans: enc [c][p] (fp32) -> encH [p][c] (f16) -- halves gather bytes
// ---------------------------------------------------------------------------
__global__ __launch_bounds__(256) void k_trans(
    const float* __restrict__ enc, unsigned short* __restrict__ encH)
{
    __shared__ float s[64 * 65];
    int t = threadIdx.x;
    int base = blockIdx.x * 64;
#pragma unroll
    for (int r = 0; r < 16; r++) {
        int idx = t + r * 256;
        int p = idx & 63, c = idx >> 6;
        s[p * 65 + c] = enc[c * HWSZ + base + p];
    }
    __syncthreads();
#pragma unroll
    for (int r = 0; r < 8; r++) {
        int idx = t + r * 256;             // 2048 pair-units
        int pr = idx & 31, p = idx >> 5;   // pair 0..31, px 0..63
        ((unsigned*)encH)[(base + p) * 32 + pr] =
            pkh(s[p * 65 + 2 * pr], s[p * 65 + 2 * pr + 1]);
    }
}

// ---------------------------------------------------------------------------
// k_deform R12: EXACT R8 structure (quad-coalesced per-pixel gather sp/g
// lane map, wave-private LDS bounce, 13/12/12/12 K-split, single-tap loop)
// with ONE delta: fp32 unpack/blend/repack (~152 VALU/tap) replaced by
// packed-f16 blend (4 cvt + 32 v_pk_fma_f16/tap, output already packed for
// the bounce). R9-R11 lesson: the n/q gather lane map de-coalesces quads
// (4 adjacent lanes -> 4 scattered pixels) and ~doubles TA/L1 time.
// ---------------------------------------------------------------------------
#define REDW 20   // reduction row stride (floats): 80B, 16B-aligned

__global__ __launch_bounds__(256) void k_deform(
    const unsigned short* __restrict__ encH, const float* __restrict__ off,
    const float* __restrict__ msk, const short* __restrict__ wA,
    float* __restrict__ rev)
{
    __shared__ __align__(16) short sm[4][16 * SROW];   // 9216 B bounce
    __shared__ __align__(16) float red[2 * 64 * REDW]; // 10240 B reduction

    int t = threadIdx.x;
    int lane = t & 63, w = t >> 6;
    int b = blockIdx.x;
    int xcd = b & 7, blk = b >> 3;          // 288 strips per xcd band
    int gy  = xcd * 24 + blk / 12;
    int gx0 = (blk % 12) * 16;

    int sp = lane >> 2, g = lane & 3;       // gather map: quad-coalesced
    int sgx  = gx0 + sp;
    int gp_s = gy * WW + sgx;
    int n = lane & 15, q = lane >> 4;       // B-frag read map
    short* smw = &sm[w][0];

    f32x4 acc[4];
#pragma unroll
    for (int ot = 0; ot < 4; ot++) acc[ot] = (f32x4){0.f, 0.f, 0.f, 0.f};

    int kstart = (w == 0) ? 0 : 13 + (w - 1) * 12;
    int kend   = (w == 0) ? 13 : kstart + 12;

    float dy = off[(2 * kstart) * HWSZ + gp_s];
    float dx = off[(2 * kstart + 1) * HWSZ + gp_s];
    float mm = msk[kstart * HWSZ + gp_s];

#pragma unroll 1
    for (int k = kstart; k < kend; k++) {
        int ky = k / 7, kx = k % 7;
        float y = (float)(gy  - 3 + ky) + dy;
        float x = (float)(sgx - 3 + kx) + dx;
        float y0f = floorf(y), x0f = floorf(x);
        float wy = y - y0f, wx = x - x0f;
        int iy0 = (int)y0f, ix0 = (int)x0f;
        int iy1 = iy0 + 1, ix1 = ix0 + 1;
        bool vy0 = (iy0 >= 0) & (iy0 < HH);
        bool vy1 = (iy1 >= 0) & (iy1 < HH);
        bool vx0 = (ix0 >= 0) & (ix0 < WW);
        bool vx1 = (ix1 >= 0) & (ix1 < WW);
        int iy0c = min(max(iy0, 0), HH - 1), iy1c = min(max(iy1, 0), HH - 1);
        int ix0c = min(max(ix0, 0), WW - 1), ix1c = min(max(ix1, 0), WW - 1);
        float a00 = (vy0 & vx0) ? (1.f - wy) * (1.f - wx) * mm : 0.f;
        float a01 = (vy0 & vx1) ? (1.f - wy) * wx * mm : 0.f;
        float a10 = (vy1 & vx0) ? wy * (1.f - wx) * mm : 0.f;
        float a11 = (vy1 & vx1) ? wy * wx * mm : 0.f;

        // f16 corners: 16 ch per lane = 2x16B per corner (quad-coalesced)
        const unsigned short* b00p = encH + (iy0c * WW + ix0c) * 64 + g * 16;
        const unsigned short* b01p = encH + (iy0c * WW + ix1c) * 64 + g * 16;
        const unsigned short* b10p = encH + (iy1c * WW + ix0c) * 64 + g * 16;
        const unsigned short* b11p = encH + (iy1c * WW + ix1c) * 64 + g * 16;
        uint4 u00[2], u01[2], u10[2], u11[2];
        u00[0] = *(const uint4*)b00p;  u00[1] = *(const uint4*)(b00p + 8);
        u01[0] = *(const uint4*)b01p;  u01[1] = *(const uint4*)(b01p + 8);
        u10[0] = *(const uint4*)b10p;  u10[1] = *(const uint4*)(b10p + 8);
        u11[0] = *(const uint4*)b11p;  u11[1] = *(const uint4*)(b11p + 8);

        // prefetch next-tap offsets
        float dyn = 0.f, dxn = 0.f, mmn = 0.f;
        if (k + 1 < kend) {
            dyn = off[(2 * k + 2) * HWSZ + gp_s];
            dxn = off[(2 * k + 3) * HWSZ + gp_s];
            mmn = msk[(k + 1) * HWSZ + gp_s];
        }

        // A-frag loads (L2-hot, independent of samples)
        h16x8 af[8];
#pragma unroll
        for (int f = 0; f < 8; f++)
            af[f] = *(const h16x8*)&wA[(k * 8 + f) * 512 + lane * 8];

        // packed-f16 blend: 4 cvt + 32 v_pk_fma_f16; output already packed
        h16x2 w00 = cvt2h(a00);
        h16x2 w01 = cvt2h(a01);
        h16x2 w10 = cvt2h(a10);
        h16x2 w11 = cvt2h(a11);

        unsigned c00[8] = {u00[0].x, u00[0].y, u00[0].z, u00[0].w,
                           u00[1].x, u00[1].y, u00[1].z, u00[1].w};
        unsigned c01[8] = {u01[0].x, u01[0].y, u01[0].z, u01[0].w,
                           u01[1].x, u01[1].y, u01[1].z, u01[1].w};
        unsigned c10[8] = {u10[0].x, u10[0].y, u10[0].z, u10[0].w,
                           u10[1].x, u10[1].y, u10[1].z, u10[1].w};
        unsigned c11[8] = {u11[0].x, u11[0].y, u11[0].z, u11[0].w,
                           u11[1].x, u11[1].y, u11[1].z, u11[1].w};
        unsigned pk[8];
#pragma unroll
        for (int j = 0; j < 8; j++) {
            h16x2 r = as_h2(c00[j]) * w00;
            r = as_h2(c01[j]) * w01 + r;
            r = as_h2(c10[j]) * w10 + r;
            r = as_h2(c11[j]) * w11 + r;
            pk[j] = as_u(r);
        }
        *(uint4*)&smw[sp * SROW + g * 16]     = make_uint4(pk[0], pk[1], pk[2], pk[3]);
        *(uint4*)&smw[sp * SROW + g * 16 + 8] = make_uint4(pk[4], pk[5], pk[6], pk[7]);

        h16x8 b0 = *(const h16x8*)&smw[n * SROW +  0 + q * 8];
        h16x8 b1 = *(const h16x8*)&smw[n * SROW + 32 + q * 8];

#pragma unroll
        for (int ot = 0; ot < 4; ot++) {
            acc[ot] = __builtin_amdgcn_mfma_f32_16x16x32_f16(af[ot * 2],     b0, acc[ot], 0, 0, 0);
            acc[ot] = __builtin_amdgcn_mfma_f32_16x16x32_f16(af[ot * 2 + 1], b1, acc[ot], 0, 0, 0);
        }

        dy = dyn; dx = dxn; mm = mmn;
    }

    // two-phase tree reduction (2-slot buffer)
    if (w >= 2) {
        float* rp = &red[((w - 2) * 64 + lane) * REDW];
#pragma unroll
        for (int ot = 0; ot < 4; ot++)
            *(float4*)&rp[ot * 4] = make_float4(acc[ot][0], acc[ot][1], acc[ot][2], acc[ot][3]);
    }
    __syncthreads();
    if (w < 2) {
        const float* rp = &red[(w * 64 + lane) * REDW];
#pragma unroll
        for (int ot = 0; ot < 4; ot++) {
            float4 v = *(const float4*)&rp[ot * 4];
            acc[ot][0] += v.x; acc[ot][1] += v.y;
            acc[ot][2] += v.z; acc[ot][3] += v.w;
        }
    }
    __syncthreads();
    if (w == 1) {
        float* rp = &red[lane * REDW];
#pragma unroll
        for (int ot = 0; ot < 4; ot++)
            *(float4*)&rp[ot * 4] = make_float4(acc[ot][0], acc[ot][1], acc[ot][2], acc[ot][3]);
    }
    __syncthreads();
    if (w == 0) {
        const float* rp = &red[lane * REDW];
#pragma unroll
        for (int ot = 0; ot < 4; ot++) {
            float4 v = *(const float4*)&rp[ot * 4];
            acc[ot][0] += v.x; acc[ot][1] += v.y;
            acc[ot][2] += v.z; acc[ot][3] += v.w;
        }
        int gp_m = gy * WW + gx0 + n;
#pragma unroll
        for (int ot = 0; ot < 4; ot++) {
            float4 rv = make_float4(acc[ot][0], acc[ot][1], acc[ot][2], acc[ot][3]);
            *(float4*)&rev[gp_m * 64 + ot * 16 + q * 4] = rv;
        }
    }
}

// ---------------------------------------------------------------------------
// k_fft: per 8x8 patch: proj_in via MFMA f16, then circular conv (fp32).
// Stages straight from f16 encH (plain 16B copies, no packing).
// ---------------------------------------------------------------------------
__global__ __launch_bounds__(256) void k_fft(
    const unsigned short* __restrict__ encH, const short* __restrict__ wpiA,
    const float* __restrict__ krT, float* __restrict__ e1)
{
    __shared__ __align__(16) short sbf[64 * SROW];   // f16 enc [px][c]
    __shared__ __align__(16) float e0[64 * ROWP];    // fp32 [px][o]
    int t = threadIdx.x;
    int pbx = blockIdx.x % 24, pby = blockIdx.x / 24;
    int gx0 = pbx * 8, gy0 = pby * 8;

#pragma unroll
    for (int r = 0; r < 2; r++) {
        int idx = t + r * 256;             // 512 x 8-ch units
        int px = idx >> 3, g8 = idx & 7;
        int gy = gy0 + (px >> 3), gx = gx0 + (px & 7);
        *(uint4*)&sbf[px * SROW + g8 * 8] =
            *(const uint4*)&encH[(gy * WW + gx) * 64 + g8 * 8];
    }
    __syncthreads();

    int lane = t & 63, w = t >> 6;
    int n = lane & 15, q = lane >> 4;
    h16x8 a0 = *(const h16x8*)&wpiA[(w * 2 + 0) * 512 + lane * 8];
    h16x8 a1 = *(const h16x8*)&wpiA[(w * 2 + 1) * 512 + lane * 8];
#pragma unroll
    for (int j = 0; j < 4; j++) {
        h16x8 b0 = *(const h16x8*)&sbf[(j * 16 + n) * SROW +  0 + q * 8];
        h16x8 b1 = *(const h16x8*)&sbf[(j * 16 + n) * SROW + 32 + q * 8];
        f32x4 acc = {0.f, 0.f, 0.f, 0.f};
        acc = __builtin_amdgcn_mfma_f32_16x16x32_f16(a0, b0, acc, 0, 0, 0);
        acc = __builtin_amdgcn_mfma_f32_16x16x32_f16(a1, b1, acc, 0, 0, 0);
#pragma unroll
        for (int r = 0; r < 4; r++)
            e0[(j * 16 + n) * ROWP + w * 16 + q * 4 + r] = acc[r];
    }
    __syncthreads();

    int o = t & 63;
    int yb = t >> 6;
#pragma unroll
    for (int yy = 0; yy < 2; yy++) {
        int y = yb + yy * 4;
        float outr[8];
#pragma unroll
        for (int x = 0; x < 8; x++) outr[x] = 0.f;
#pragma unroll
        for (int u = 0; u < 8; u++) {
            int ry = (y - u + 8) & 7;
            float row[8];
#pragma unroll
            for (int rx = 0; rx < 8; rx++)
                row[rx] = e0[(ry * 8 + rx) * ROWP + o];
#pragma unroll
            for (int v = 0; v < 8; v++) {
                float kv = krT[(u * 8 + v) * 64 + o];
#pragma unroll
                for (int x = 0; x < 8; x++)
                    outr[x] += kv * row[(x - v + 8) & 7];
            }
        }
        int gy = gy0 + y;
#pragma unroll
        for (int x = 0; x < 8; x++)
            e1[(gy * WW + gx0 + x) * 64 + o] = outr[x];
    }
}

// ---------------------------------------------------------------------------
// k_c3out: fused conv3x3(e1+rev) -> [.,dec] -> proj_out -> SimpleGate.
// ---------------------------------------------------------------------------
__global__ __launch_bounds__(256) void k_c3out(
    const float* __restrict__ e1, const float* __restrict__ rev,
    const short* __restrict__ w2A, const float* __restrict__ dec,
    const short* __restrict__ wpoA, float* __restrict__ out)
{
    __shared__ __align__(16) short sm[4][54 * C3ROW];  // per-wave: 3 rows x 18 px
    int t = threadIdx.x;
    int lane = t & 63, w = t >> 6;
    int b = blockIdx.x;
    int xcd = b & 7, blk = b >> 3;
    int gy  = xcd * 24 + blk / 3;
    int gx0 = (blk % 3) * 64 + w * 16;
    short* smw = &sm[w][0];
    int n = lane & 15, q = lane >> 4;

    for (int r = 0; r < 14; r++) {
        int u = lane + r * 64;
        if (u < 864) {
            int rp = u >> 4, g = u & 15;
            int row = rp / 18, pxl = rp - row * 18;
            int gyy = gy + row - 1, gxx = gx0 + pxl - 1;
            float4 v = make_float4(0.f, 0.f, 0.f, 0.f);
            if (gyy >= 0 && gyy < HH && gxx >= 0 && gxx < WW) {
                int gp = (gyy * WW + gxx) * 64 + g * 4;
                float4 va = *(const float4*)&e1[gp];
                float4 vb = *(const float4*)&rev[gp];
                v.x = va.x + vb.x; v.y = va.y + vb.y;
                v.z = va.z + vb.z; v.w = va.w + vb.w;
            }
            *(uint2*)&smw[rp * C3ROW + g * 4] = make_uint2(pkh(v.x, v.y), pkh(v.z, v.w));
        }
    }

    f32x4 acc[4];
#pragma unroll
    for (int ot = 0; ot < 4; ot++) acc[ot] = (f32x4){0.f, 0.f, 0.f, 0.f};

#pragma unroll 1
    for (int tap = 0; tap < 9; tap++) {
        int dy = tap / 3, dx = tap - dy * 3;
        int rp = dy * 18 + n + dx;
        h16x8 b0 = *(const h16x8*)&smw[rp * C3ROW +  0 + q * 8];
        h16x8 b1 = *(const h16x8*)&smw[rp * C3ROW + 32 + q * 8];
#pragma unroll
        for (int ot = 0; ot < 4; ot++) {
            h16x8 a0 = *(const h16x8*)&w2A[(tap * 8 + ot * 2 + 0) * 512 + lane * 8];
            h16x8 a1 = *(const h16x8*)&w2A[(tap * 8 + ot * 2 + 1) * 512 + lane * 8];
            acc[ot] = __builtin_amdgcn_mfma_f32_16x16x32_f16(a0, b0, acc[ot], 0, 0, 0);
            acc[ot] = __builtin_amdgcn_mfma_f32_16x16x32_f16(a1, b1, acc[ot], 0, 0, 0);
        }
    }

    // fused proj_out: stage e3 (C-layout regs) + dec into B-frag rows
#pragma unroll
    for (int ot = 0; ot < 4; ot++) {
        unsigned lo = pkh(acc[ot][0], acc[ot][1]);
        unsigned hi = pkh(acc[ot][2], acc[ot][3]);
        *(uint2*)&smw[n * OROW + ot * 16 + q * 4] = make_uint2(lo, hi);
    }
    {
        int gp = gy * WW + gx0 + n;
        unsigned pk[8];
#pragma unroll
        for (int i = 0; i < 8; i++) {
            float va = dec[(q * 16 + 2 * i)     * HWSZ + gp];
            float vb = dec[(q * 16 + 2 * i + 1) * HWSZ + gp];
            pk[i] = pkh(va, vb);
        }
        *(uint4*)&smw[n * OROW + 64 + q * 16]     = make_uint4(pk[0], pk[1], pk[2], pk[3]);
        *(uint4*)&smw[n * OROW + 64 + q * 16 + 8] = make_uint4(pk[4], pk[5], pk[6], pk[7]);
    }

    f32x4 go[8];
#pragma unroll
    for (int ot = 0; ot < 8; ot++) go[ot] = (f32x4){0.f, 0.f, 0.f, 0.f};

#pragma unroll 1
    for (int kt = 0; kt < 4; kt++) {
        h16x8 bb = *(const h16x8*)&smw[n * OROW + kt * 32 + q * 8];
#pragma unroll
        for (int ot = 0; ot < 8; ot++) {
            h16x8 aa = *(const h16x8*)&wpoA[(ot * 4 + kt) * 512 + lane * 8];
            go[ot] = __builtin_amdgcn_mfma_f32_16x16x32_f16(aa, bb, go[ot], 0, 0, 0);
        }
    }

    int gp = gy * WW + gx0 + n;
#pragma unroll
    for (int ot = 0; ot < 4; ot++)
#pragma unroll
        for (int r = 0; r < 4; r++)
            out[(ot * 16 + q * 4 + r) * HWSZ + gp] = go[ot][r] * go[ot + 4][r];
}

// ---------------------------------------------------------------------------
extern "C" void kernel_launch(void* const* d_in, const int* in_sizes, int n_in,
                              void* d_out, int out_size, void* d_ws, size_t ws_size,
                              hipStream_t stream)
{
    const float* enc  = (const float*)d_in[0];
    const float* dec  = (const float*)d_in[1];
    const float* ioff = (const float*)d_in[2];
    const float* iwt  = (const float*)d_in[3];
    const float* wpi  = (const float*)d_in[4];
    const float* fw   = (const float*)d_in[5];
    const float* wpo  = (const float*)d_in[6];
    const float* wd   = (const float*)d_in[7];
    const float* wc1  = (const float*)d_in[8];
    const float* wc2  = (const float*)d_in[9];
    float* out = (float*)d_out;
    float* ws  = (float*)d_ws;

    float*          krT  = ws;                           //    4096
    float*          rev  = ws + 4096;                    // 2359296  [px][64]
    float*          e1   = ws + 2363392;                 // 2359296  [px][64]
    unsigned short* encH = (unsigned short*)(ws + 4722688); // 2359296 f16 (1179648 fl)
    short*          wA   = (short*)(ws + 5902336);       // 200704 f16
    short*          w2A  = (short*)(ws + 6002688);       //  36864 f16
    short*          wpoA = (short*)(ws + 6021120);       //  16384 f16
    short*          wpiA = (short*)(ws + 6029312);       //   4096 f16

    hipLaunchKernelGGL(k_prep,   dim3(49),   dim3(256), 0, stream,
                       fw, wd, wc2, wc1, wpo, wpi, krT, wA, w2A, wpoA, wpiA);
    hipLaunchKernelGGL(k_trans,  dim3(576),  dim3(256), 0, stream, enc, encH);
    hipLaunchKernelGGL(k_deform, dim3(2304), dim3(256), 0, stream, encH, ioff, iwt, wA, rev);
    hipLaunchKernelGGL(k_fft,    dim3(576),  dim3(256), 0, stream, encH, wpiA, krT, e1);
    hipLaunchKernelGGL(k_c3out,  dim3(576),  dim3(256), 0, stream, e1, rev, w2A, dec, wpoA, out);
}